// Round 2
// baseline (994.575 us; speedup 1.0000x reference)
//
#include <hip/hip_runtime.h>
#include <hip/hip_bf16.h>
#include <math.h>

// Problem constants
constexpr int Bn = 16;
constexpr int Ln = 512;
constexpr int Hn = 1024;
constexpr int RowsT = Bn * Ln;  // 8192

typedef __attribute__((ext_vector_type(8))) short bf16x8;           // 8 bf16 (4 VGPRs)
typedef __attribute__((ext_vector_type(4))) float f32x4;            // MFMA C/D
typedef __attribute__((ext_vector_type(8))) unsigned short u16x8;

__device__ __forceinline__ unsigned short f2bf(float f) {  // RNE f32->bf16
  unsigned u = __float_as_uint(f);
  u += 0x7FFFu + ((u >> 16) & 1u);
  return (unsigned short)(u >> 16);
}

__device__ __forceinline__ void gload_lds16(const void* g, void* l) {
  __builtin_amdgcn_global_load_lds(
      (const __attribute__((address_space(1))) void*)g,
      (__attribute__((address_space(3))) void*)l, 16, 0, 0);
}

// ---------------- block-wide reduction ----------------
__device__ __forceinline__ float block_reduce_sum(float v) {
  __shared__ float sbuf[8];
  const int lane = threadIdx.x & 63;
  const int wid = threadIdx.x >> 6;
#pragma unroll
  for (int off = 32; off > 0; off >>= 1) v += __shfl_down(v, off, 64);
  __syncthreads();
  if (lane == 0) sbuf[wid] = v;
  __syncthreads();
  if (threadIdx.x == 0) {
    float t = 0.f;
    const int nw = (blockDim.x + 63) >> 6;
    for (int i = 0; i < nw; ++i) t += sbuf[i];
    sbuf[0] = t;
  }
  __syncthreads();
  return sbuf[0];
}

// ---------- elementwise f32 -> bf16 (8/thread) ----------
__global__ __launch_bounds__(256) void f32_to_bf16_kernel(
    const float* __restrict__ in, unsigned short* __restrict__ out) {
  const size_t i = ((size_t)blockIdx.x * blockDim.x + threadIdx.x) * 8;
  const float4 a = *(const float4*)(in + i);
  const float4 b = *(const float4*)(in + i + 4);
  u16x8 r;
  r[0] = f2bf(a.x); r[1] = f2bf(a.y); r[2] = f2bf(a.z); r[3] = f2bf(a.w);
  r[4] = f2bf(b.x); r[5] = f2bf(b.y); r[6] = f2bf(b.z); r[7] = f2bf(b.w);
  *(u16x8*)(out + i) = r;
}

// ---------- W[K][N] f32 -> Wt[N][K] bf16 ----------
__global__ __launch_bounds__(256) void transpose_w_bf16(
    const float* __restrict__ W, unsigned short* __restrict__ Wt, int K, int N) {
  __shared__ float t[32][33];
  const int n0 = blockIdx.x * 32;
  const int k0 = blockIdx.y * 32;
  const int tx = threadIdx.x & 31;
  const int ty = threadIdx.x >> 5;  // 0..7
#pragma unroll
  for (int i = 0; i < 32; i += 8)
    t[ty + i][tx] = W[(size_t)(k0 + ty + i) * N + n0 + tx];
  __syncthreads();
#pragma unroll
  for (int i = 0; i < 32; i += 8)
    Wt[(size_t)(n0 + ty + i) * K + k0 + tx] = f2bf(t[tx][ty + i]);
}

// ---------- bf16 MFMA GEMM: D[M][N] = A[M][K] @ Bt[N][K]^T + bias ----------
// m97 structure: 128x128 tile, BK=32, 4 waves (2x2 of 64x64), global_load_lds w16.
template<typename OutT>
__global__ __launch_bounds__(256) void mfma_gemm_bias(
    const unsigned short* __restrict__ A,   // [M][K] bf16
    const unsigned short* __restrict__ Bt,  // [N][K] bf16
    const float* __restrict__ bias,         // [N] f32
    OutT* __restrict__ D, int M, int N, int K) {
  constexpr int BK = 32;
  __shared__ unsigned short As[128][BK];  // 8KB, linear (global_load_lds needs it)
  __shared__ unsigned short Bs[128][BK];  // 8KB
  const int tid = threadIdx.x;
  const int wid = tid >> 6;
  const int lane = tid & 63;
  const int row0 = blockIdx.y * 128;
  const int col0 = blockIdx.x * 128;
  const int wr = (wid >> 1) * 64;   // wave's 64x64 sub-tile
  const int wc = (wid & 1) * 64;
  // staging: wave wid fills rows [wid*32, wid*32+32) of As and Bs.
  // lane writes LDS base + lane*16B -> row wid*32+j*16+(lane>>2), kbyte (lane&3)*16
  const int sr = lane >> 2;         // 0..15
  const int sk = (lane & 3) * 8;    // k element offset
  const size_t arow = (size_t)(row0 + wid * 32 + sr) * K + sk;
  const size_t brow = (size_t)(col0 + wid * 32 + sr) * K + sk;

  f32x4 acc[4][4] = {};

  for (int k0 = 0; k0 < K; k0 += BK) {
    gload_lds16(A + arow + k0,                   &As[wid * 32][0]);
    gload_lds16(A + arow + (size_t)16 * K + k0,  &As[wid * 32 + 16][0]);
    gload_lds16(Bt + brow + k0,                  &Bs[wid * 32][0]);
    gload_lds16(Bt + brow + (size_t)16 * K + k0, &Bs[wid * 32 + 16][0]);
    __syncthreads();  // drains vmcnt -> staged data visible
    bf16x8 af[4], bfr[4];
#pragma unroll
    for (int m = 0; m < 4; ++m)
      af[m] = *(const bf16x8*)&As[wr + m * 16 + (lane & 15)][(lane >> 4) * 8];
#pragma unroll
    for (int n = 0; n < 4; ++n)
      bfr[n] = *(const bf16x8*)&Bs[wc + n * 16 + (lane & 15)][(lane >> 4) * 8];
#pragma unroll
    for (int m = 0; m < 4; ++m)
#pragma unroll
      for (int n = 0; n < 4; ++n)
        acc[m][n] = __builtin_amdgcn_mfma_f32_16x16x32_bf16(af[m], bfr[n], acc[m][n], 0, 0, 0);
    __syncthreads();
  }
  // C/D layout (m89/m91 verified): col = lane&15, row = (lane>>4)*4 + reg
  const int cr = (lane >> 4) * 4;
  const int cc = lane & 15;
#pragma unroll
  for (int m = 0; m < 4; ++m) {
#pragma unroll
    for (int n = 0; n < 4; ++n) {
      const int gc = col0 + wc + n * 16 + cc;
      const float bv = bias[gc];
#pragma unroll
      for (int r = 0; r < 4; ++r) {
        const int gr = row0 + wr + m * 16 + cr + r;
        const float v = acc[m][n][r] + bv;
        if constexpr (sizeof(OutT) == 2) {
          D[(size_t)gr * N + gc] = (OutT)f2bf(v);
        } else {
          D[(size_t)gr * N + gc] = v;
        }
      }
    }
  }
}

#define TS 64
#define KT 16
#define PAD 4

// ---------- Q[b,t,o] = exp( 20 * <tar[b,t,:],fc[b,o,:]> * rt * rf ) ----------
__global__ __launch_bounds__(256) void gemm_cos_exp_kernel(
    const float* __restrict__ Tar, const float* __restrict__ Fc,
    const float* __restrict__ rt, const float* __restrict__ rf,
    float* __restrict__ Q) {
  __shared__ float As[KT][TS + PAD];
  __shared__ float Bs[KT][TS + PAD];
  const int b = blockIdx.z;
  const float* Ab = Tar + (size_t)b * Ln * Hn;
  const float* Bb = Fc + (size_t)b * Ln * Hn;
  float* Qb = Q + (size_t)b * Ln * Ln;
  const int t0 = blockIdx.y * TS, o0 = blockIdx.x * TS;
  const int tid = threadIdx.x;
  const int ty = tid >> 4, tx = tid & 15;
  float acc[4][4] = {};
  for (int k0 = 0; k0 < Hn; k0 += KT) {
#pragma unroll
    for (int i = 0; i < 4; ++i) {
      int idx = tid + i * 256;
      int m = idx >> 4, kk = idx & 15;
      As[kk][m] = Ab[(size_t)(t0 + m) * Hn + (k0 + kk)];
      Bs[kk][m] = Bb[(size_t)(o0 + m) * Hn + (k0 + kk)];
    }
    __syncthreads();
#pragma unroll
    for (int kk = 0; kk < KT; ++kk) {
      float a[4], bb[4];
#pragma unroll
      for (int i = 0; i < 4; ++i) a[i] = As[kk][ty * 4 + i];
#pragma unroll
      for (int j = 0; j < 4; ++j) bb[j] = Bs[kk][tx * 4 + j];
#pragma unroll
      for (int i = 0; i < 4; ++i)
#pragma unroll
        for (int j = 0; j < 4; ++j) acc[i][j] += a[i] * bb[j];
    }
    __syncthreads();
  }
#pragma unroll
  for (int i = 0; i < 4; ++i) {
    const int t = t0 + ty * 4 + i;
#pragma unroll
    for (int j = 0; j < 4; ++j) {
      const int o = o0 + tx * 4 + j;
      const float c = acc[i][j] * rt[b * Ln + t] * rf[b * Ln + o] * 20.0f;
      Qb[(size_t)t * Ln + o] = expf(c);
    }
  }
}

// ---------- Out[b,t,h] = rn[b,t] * sum_o Q[b,t,o]*Tp[b,o,h] + Tar[b,t,h] ----------
__global__ __launch_bounds__(256) void gemm_out_kernel(
    const float* __restrict__ Q, const float* __restrict__ Tp,
    const float* __restrict__ rn, const float* __restrict__ Tar,
    float* __restrict__ Out) {
  __shared__ float As[KT][TS + PAD];
  __shared__ float Bs[KT][TS + PAD];
  const int b = blockIdx.z;
  const float* Ab = Q + (size_t)b * Ln * Ln;
  const float* Bb = Tp + (size_t)b * Ln * Hn;
  const int t0 = blockIdx.y * TS, h0 = blockIdx.x * TS;
  const int tid = threadIdx.x;
  const int ty = tid >> 4, tx = tid & 15;
  float acc[4][4] = {};
  for (int k0 = 0; k0 < Ln; k0 += KT) {
#pragma unroll
    for (int i = 0; i < 4; ++i) {
      int idx = tid + i * 256;
      int m = idx >> 4, kk = idx & 15;
      As[kk][m] = Ab[(size_t)(t0 + m) * Ln + (k0 + kk)];
    }
#pragma unroll
    for (int i = 0; i < 4; ++i) {
      int idx = tid + i * 256;
      int kk = idx >> 6, n = idx & 63;
      Bs[kk][n] = Bb[(size_t)(k0 + kk) * Hn + (h0 + n)];
    }
    __syncthreads();
#pragma unroll
    for (int kk = 0; kk < KT; ++kk) {
      float a[4], bb[4];
#pragma unroll
      for (int i = 0; i < 4; ++i) a[i] = As[kk][ty * 4 + i];
#pragma unroll
      for (int j = 0; j < 4; ++j) bb[j] = Bs[kk][tx * 4 + j];
#pragma unroll
      for (int i = 0; i < 4; ++i)
#pragma unroll
        for (int j = 0; j < 4; ++j) acc[i][j] += a[i] * bb[j];
    }
    __syncthreads();
  }
#pragma unroll
  for (int i = 0; i < 4; ++i) {
    const int t = t0 + ty * 4 + i;
    const float s = rn[b * Ln + t];
#pragma unroll
    for (int j = 0; j < 4; ++j) {
      const int h = h0 + tx * 4 + j;
      const size_t off = ((size_t)b * Ln + t) * Hn + h;
      Out[off] = acc[i][j] * s + Tar[off];
    }
  }
}

// ---------- r[row] = 1 / max(||X_row||_2, eps) ----------
__global__ __launch_bounds__(256) void rownorm_recip_kernel(
    const float* __restrict__ X, float* __restrict__ r, int len, float eps) {
  const float* row = X + (size_t)blockIdx.x * len;
  float s = 0.f;
  for (int i = threadIdx.x; i < len; i += blockDim.x) {
    float v = row[i];
    s += v * v;
  }
  s = block_reduce_sum(s);
  if (threadIdx.x == 0) r[blockIdx.x] = 1.0f / fmaxf(sqrtf(s), eps);
}

// ---------- Sinkhorn row normalize ----------
__global__ __launch_bounds__(256) void sink_row_kernel(float* __restrict__ Q) {
  float* row = Q + (size_t)blockIdx.x * Ln;
  const int tid = threadIdx.x;
  float v0 = row[tid];
  float v1 = row[tid + 256];
  float s = block_reduce_sum(v0 + v1);
  float inv = 1.0f / s;
  row[tid] = v0 * inv;
  row[tid + 256] = v1 * inv;
}

// ---------- Sinkhorn col normalize ----------
__global__ __launch_bounds__(256) void sink_col_kernel(float* __restrict__ Q) {
  const int b = blockIdx.y;
  float* Qb = Q + (size_t)b * Ln * Ln;
  const int o = blockIdx.x * 256 + threadIdx.x;
  float s0 = 0.f, s1 = 0.f, s2 = 0.f, s3 = 0.f;
  for (int t = 0; t < Ln; t += 4) {
    s0 += Qb[(size_t)(t + 0) * Ln + o];
    s1 += Qb[(size_t)(t + 1) * Ln + o];
    s2 += Qb[(size_t)(t + 2) * Ln + o];
    s3 += Qb[(size_t)(t + 3) * Ln + o];
  }
  const float inv = 1.0f / (s0 + s1 + s2 + s3);
  for (int t = 0; t < Ln; ++t) Qb[(size_t)t * Ln + o] *= inv;
}

// ---------- LayerNorm over last dim, in-place ----------
__global__ __launch_bounds__(256) void ln_kernel(
    float* __restrict__ Out, const float* __restrict__ g, const float* __restrict__ b) {
  float* row = Out + (size_t)blockIdx.x * Hn;
  const int tid = threadIdx.x;
  float4 v = reinterpret_cast<float4*>(row)[tid];
  float s = v.x + v.y + v.z + v.w;
  float ss = v.x * v.x + v.y * v.y + v.z * v.z + v.w * v.w;
  const float tot = block_reduce_sum(s);
  const float tot2 = block_reduce_sum(ss);
  const float mu = tot * (1.0f / Hn);
  const float var = tot2 * (1.0f / Hn) - mu * mu;
  const float rs = rsqrtf(var + 1e-5f);
  const float4 gg = reinterpret_cast<const float4*>(g)[tid];
  const float4 bb = reinterpret_cast<const float4*>(b)[tid];
  v.x = (v.x - mu) * rs * gg.x + bb.x;
  v.y = (v.y - mu) * rs * gg.y + bb.y;
  v.z = (v.z - mu) * rs * gg.z + bb.z;
  v.w = (v.w - mu) * rs * gg.w + bb.w;
  reinterpret_cast<float4*>(row)[tid] = v;
}

extern "C" void kernel_launch(void* const* d_in, const int* in_sizes, int n_in,
                              void* d_out, int out_size, void* d_ws, size_t ws_size,
                              hipStream_t stream) {
  const float* origin = (const float*)d_in[0];
  const float* target = (const float*)d_in[1];
  const float* W_ori = (const float*)d_in[2];
  const float* b_ori = (const float*)d_in[3];
  const float* W_tar = (const float*)d_in[4];
  const float* b_tar = (const float*)d_in[5];
  const float* W_ft = (const float*)d_in[6];
  const float* b_ft = (const float*)d_in[7];
  const float* W_fo = (const float*)d_in[8];
  const float* b_fo = (const float*)d_in[9];
  const float* W_fot = (const float*)d_in[10];
  const float* b_fot = (const float*)d_in[11];
  const float* ln_g = (const float*)d_in[12];
  const float* ln_b = (const float*)d_in[13];
  float* out = (float*)d_out;

  // ---- workspace layout, 82.1 MB total (lifetime-overlapped) ----
  // [0,32M):       tar (f32, live to end)
  // [32M,64M):     obf|t1_bf (bf16, early)  ->  tp (f32, from GEMM5 to end)
  // [64M,80M):     ori_bf (bf16, GEMM1..GEMM5) -> Qw (f32, cos-GEMM to end)
  // [80M,82M):     Wt (bf16 transposed weight, serially reused)
  // [82M,82.1M):   rt, rf, rn
  char* ws = (char*)d_ws;
  float* tar = (float*)(ws + 0);
  unsigned short* P0 = (unsigned short*)(ws + 33554432);
  unsigned short* P1 = (unsigned short*)(ws + 33554432 + 16777216);
  float* tp = (float*)(ws + 33554432);
  unsigned short* oribf = (unsigned short*)(ws + 67108864);
  float* Qw = (float*)(ws + 67108864);
  unsigned short* Wt = (unsigned short*)(ws + 83886080);
  float* rt = (float*)(ws + 85983232);
  float* rf = rt + RowsT;
  float* rn = rf + RowsT;
  float* fc = (float*)d_out;  // ori_fc lives in d_out, dead before gemm_out

  const dim3 blk(256);
  const dim3 gConv(RowsT * Hn / (256 * 8));      // 4096
  const dim3 gTr(Hn / 32, Hn / 32);              // (32,32)
  const dim3 gMM(Hn / 128, RowsT / 128);         // (8,64)

  // ori = origin @ W_ori + b_ori   (bf16 out)
  f32_to_bf16_kernel<<<gConv, blk, 0, stream>>>(origin, P0);
  transpose_w_bf16<<<gTr, blk, 0, stream>>>(W_ori, Wt, Hn, Hn);
  mfma_gemm_bias<unsigned short><<<gMM, blk, 0, stream>>>(P0, Wt, b_ori, oribf, RowsT, Hn, Hn);
  // t1 = target @ W_tar + b_tar   (bf16 out)
  f32_to_bf16_kernel<<<gConv, blk, 0, stream>>>(target, P0);
  transpose_w_bf16<<<gTr, blk, 0, stream>>>(W_tar, Wt, Hn, Hn);
  mfma_gemm_bias<unsigned short><<<gMM, blk, 0, stream>>>(P0, Wt, b_tar, P1, RowsT, Hn, Hn);
  // tar = t1 @ W_ft + b_ft        (f32 out)
  transpose_w_bf16<<<gTr, blk, 0, stream>>>(W_ft, Wt, Hn, Hn);
  mfma_gemm_bias<float><<<gMM, blk, 0, stream>>>(P1, Wt, b_ft, tar, RowsT, Hn, Hn);
  // ori_fc = ori @ W_fo + b_fo    (f32 out, in d_out)
  transpose_w_bf16<<<gTr, blk, 0, stream>>>(W_fo, Wt, Hn, Hn);
  mfma_gemm_bias<float><<<gMM, blk, 0, stream>>>(oribf, Wt, b_fo, fc, RowsT, Hn, Hn);
  // ori_tp = ori @ W_fot + b_fot  (f32 out; overwrites dead P0/P1)
  transpose_w_bf16<<<gTr, blk, 0, stream>>>(W_fot, Wt, Hn, Hn);
  mfma_gemm_bias<float><<<gMM, blk, 0, stream>>>(oribf, Wt, b_fot, tp, RowsT, Hn, Hn);

  // cosine norms
  rownorm_recip_kernel<<<dim3(RowsT), blk, 0, stream>>>(tar, rt, Hn, 1e-8f);
  rownorm_recip_kernel<<<dim3(RowsT), blk, 0, stream>>>(fc, rf, Hn, 1e-8f);

  // Q = exp(cos/0.05)  (overwrites dead ori_bf)
  gemm_cos_exp_kernel<<<dim3(Ln / TS, Ln / TS, Bn), blk, 0, stream>>>(tar, fc, rt, rf, Qw);

  // 5 Sinkhorn iterations
  for (int it = 0; it < 5; ++it) {
    sink_row_kernel<<<dim3(Bn * Ln), blk, 0, stream>>>(Qw);
    sink_col_kernel<<<dim3(Ln / 256, Bn), blk, 0, stream>>>(Qw);
  }

  // plan row norms
  rownorm_recip_kernel<<<dim3(RowsT), blk, 0, stream>>>(Qw, rn, Ln, 1e-12f);

  // out = plan @ ori_tp + tar   (fc in d_out is dead by now)
  gemm_out_kernel<<<dim3(Hn / TS, Ln / TS, Bn), blk, 0, stream>>>(Qw, tp, rn, tar, out);

  // LayerNorm in-place
  ln_kernel<<<dim3(RowsT), blk, 0, stream>>>(out, ln_g, ln_b);
}

// Round 3
// 542.449 us; speedup vs baseline: 1.8335x; 1.8335x over previous
//
#include <hip/hip_runtime.h>
#include <hip/hip_bf16.h>
#include <math.h>

// Problem constants
constexpr int Bn = 16;
constexpr int Ln = 512;
constexpr int Hn = 1024;
constexpr int RowsT = Bn * Ln;  // 8192

typedef __attribute__((ext_vector_type(8))) short bf16x8;
typedef __attribute__((ext_vector_type(4))) float f32x4;
typedef __attribute__((ext_vector_type(8))) unsigned short u16x8;

__device__ __forceinline__ unsigned short f2bf(float f) {  // RNE f32->bf16
  unsigned u = __float_as_uint(f);
  u += 0x7FFFu + ((u >> 16) & 1u);
  return (unsigned short)(u >> 16);
}
__device__ __forceinline__ float bf2f(unsigned short u) {
  return __uint_as_float(((unsigned)u) << 16);
}

__device__ __forceinline__ void gload_lds16(const void* g, void* l) {
  __builtin_amdgcn_global_load_lds(
      (const __attribute__((address_space(1))) void*)g,
      (__attribute__((address_space(3))) void*)l, 16, 0, 0);
}

// ---------------- block-wide reduction ----------------
__device__ __forceinline__ float block_reduce_sum(float v) {
  __shared__ float sbuf[8];
  const int lane = threadIdx.x & 63;
  const int wid = threadIdx.x >> 6;
#pragma unroll
  for (int off = 32; off > 0; off >>= 1) v += __shfl_down(v, off, 64);
  __syncthreads();
  if (lane == 0) sbuf[wid] = v;
  __syncthreads();
  if (threadIdx.x == 0) {
    float t = 0.f;
    const int nw = (blockDim.x + 63) >> 6;
    for (int i = 0; i < nw; ++i) t += sbuf[i];
    sbuf[0] = t;
  }
  __syncthreads();
  return sbuf[0];
}

// ---------- elementwise f32 -> bf16 (8/thread) ----------
__global__ __launch_bounds__(256) void f32_to_bf16_kernel(
    const float* __restrict__ in, unsigned short* __restrict__ out) {
  const size_t i = ((size_t)blockIdx.x * blockDim.x + threadIdx.x) * 8;
  const float4 a = *(const float4*)(in + i);
  const float4 b = *(const float4*)(in + i + 4);
  u16x8 r;
  r[0] = f2bf(a.x); r[1] = f2bf(a.y); r[2] = f2bf(a.z); r[3] = f2bf(a.w);
  r[4] = f2bf(b.x); r[5] = f2bf(b.y); r[6] = f2bf(b.z); r[7] = f2bf(b.w);
  *(u16x8*)(out + i) = r;
}

// ---------- W[K][N] f32 -> Wt[N][K] bf16 ----------
__global__ __launch_bounds__(256) void transpose_w_bf16(
    const float* __restrict__ W, unsigned short* __restrict__ Wt, int K, int N) {
  __shared__ float t[32][33];
  const int n0 = blockIdx.x * 32;
  const int k0 = blockIdx.y * 32;
  const int tx = threadIdx.x & 31;
  const int ty = threadIdx.x >> 5;
#pragma unroll
  for (int i = 0; i < 32; i += 8)
    t[ty + i][tx] = W[(size_t)(k0 + ty + i) * N + n0 + tx];
  __syncthreads();
#pragma unroll
  for (int i = 0; i < 32; i += 8)
    Wt[(size_t)(n0 + ty + i) * K + k0 + tx] = f2bf(t[tx][ty + i]);
}

// ---------- per-batch bf16 transpose: in[b][512][1024] -> out[b][1024][512] ----------
__global__ __launch_bounds__(256) void transpose_act_bf16(
    const unsigned short* __restrict__ in, unsigned short* __restrict__ out) {
  __shared__ unsigned short t[32][34];  // stride 34 ushorts (17 dwords) -> conflict-free
  const int b = blockIdx.z;
  const int h0 = blockIdx.x * 32;
  const int o0 = blockIdx.y * 32;
  const int tx = threadIdx.x & 31;
  const int ty = threadIdx.x >> 5;
  const unsigned short* ib = in + (size_t)b * Ln * Hn;
  unsigned short* ob = out + (size_t)b * Hn * Ln;
#pragma unroll
  for (int i = 0; i < 32; i += 8)
    t[ty + i][tx] = ib[(size_t)(o0 + ty + i) * Hn + h0 + tx];
  __syncthreads();
#pragma unroll
  for (int i = 0; i < 32; i += 8)
    ob[(size_t)(h0 + ty + i) * Ln + o0 + tx] = t[tx][ty + i];
}

// ================= MFMA GEMM bodies (m97 structure: 128x128, BK=32) =================
// A [.][K] k-contig, Bt [.][K] k-contig; 4 waves as 2x2 of 64x64.

#define MFMA_PROLOG(Aptr, Bptr, Kdim)                                          \
  constexpr int BK = 32;                                                       \
  __shared__ unsigned short As[128][BK];                                       \
  __shared__ unsigned short Bs[128][BK];                                       \
  const int tid = threadIdx.x;                                                 \
  const int wid = tid >> 6;                                                    \
  const int lane = tid & 63;                                                   \
  const int wr = (wid >> 1) * 64;                                              \
  const int wc = (wid & 1) * 64;                                               \
  const int sr = lane >> 2;                                                    \
  const int sk = (lane & 3) * 8;                                               \
  const size_t arow = (size_t)(row0 + wid * 32 + sr) * Kdim + sk;              \
  const size_t brow = (size_t)(col0 + wid * 32 + sr) * Kdim + sk;              \
  f32x4 acc[4][4] = {};                                                        \
  for (int k0 = 0; k0 < Kdim; k0 += BK) {                                      \
    gload_lds16(Aptr + arow + k0,                      &As[wid * 32][0]);      \
    gload_lds16(Aptr + arow + (size_t)16 * Kdim + k0,  &As[wid * 32 + 16][0]); \
    gload_lds16(Bptr + brow + k0,                      &Bs[wid * 32][0]);      \
    gload_lds16(Bptr + brow + (size_t)16 * Kdim + k0,  &Bs[wid * 32 + 16][0]); \
    __syncthreads();                                                           \
    bf16x8 af[4], bfr[4];                                                      \
    _Pragma("unroll")                                                          \
    for (int m = 0; m < 4; ++m)                                                \
      af[m] = *(const bf16x8*)&As[wr + m * 16 + (lane & 15)][(lane >> 4) * 8]; \
    _Pragma("unroll")                                                          \
    for (int n = 0; n < 4; ++n)                                                \
      bfr[n] = *(const bf16x8*)&Bs[wc + n * 16 + (lane & 15)][(lane >> 4) * 8];\
    _Pragma("unroll")                                                          \
    for (int m = 0; m < 4; ++m)                                                \
      _Pragma("unroll")                                                        \
      for (int n = 0; n < 4; ++n)                                              \
        acc[m][n] = __builtin_amdgcn_mfma_f32_16x16x32_bf16(af[m], bfr[n],     \
                                                            acc[m][n], 0, 0, 0);\
    __syncthreads();                                                           \
  }                                                                            \
  const int cr = (lane >> 4) * 4;                                              \
  const int cc = lane & 15;

// ---------- D[M][N] = A @ Bt^T + bias  (bf16 out) ----------
__global__ __launch_bounds__(256) void mfma_gemm_bias(
    const unsigned short* __restrict__ A, const unsigned short* __restrict__ Bt,
    const float* __restrict__ bias, unsigned short* __restrict__ D,
    int N, int K) {
  const int row0 = blockIdx.y * 128;
  const int col0 = blockIdx.x * 128;
  MFMA_PROLOG(A, Bt, K)
#pragma unroll
  for (int m = 0; m < 4; ++m) {
#pragma unroll
    for (int n = 0; n < 4; ++n) {
      const int gc = col0 + wc + n * 16 + cc;
      const float bv = bias[gc];
#pragma unroll
      for (int r = 0; r < 4; ++r) {
        const int gr = row0 + wr + m * 16 + cr + r;
        D[(size_t)gr * N + gc] = f2bf(acc[m][n][r] + bv);
      }
    }
  }
}

// ---------- Q[b][t][o] = exp(20 * <tar_t, fc_o> * rt[b,t] * rf[b,o]) ----------
__global__ __launch_bounds__(256) void mfma_cos_exp(
    const unsigned short* __restrict__ TarBf, const unsigned short* __restrict__ FcBf,
    const float* __restrict__ rt, const float* __restrict__ rf,
    float* __restrict__ Q) {
  const int b = blockIdx.z;
  const unsigned short* Ab = TarBf + (size_t)b * Ln * Hn;
  const unsigned short* Bb = FcBf + (size_t)b * Ln * Hn;
  float* Qb = Q + (size_t)b * Ln * Ln;
  const int row0 = blockIdx.y * 128;  // t
  const int col0 = blockIdx.x * 128;  // o
  MFMA_PROLOG(Ab, Bb, Hn)
#pragma unroll
  for (int m = 0; m < 4; ++m) {
#pragma unroll
    for (int n = 0; n < 4; ++n) {
      const int o = col0 + wc + n * 16 + cc;
      const float rfo = rf[b * Ln + o] * 20.0f;
#pragma unroll
      for (int r = 0; r < 4; ++r) {
        const int t = row0 + wr + m * 16 + cr + r;
        const float c = acc[m][n][r] * rt[b * Ln + t] * rfo;
        Qb[(size_t)t * Ln + o] = __expf(c);
      }
    }
  }
}

// ---------- Out[b][t][h] = plan[b][t][:] @ tpT[b][h][:]^T + tar[b][t][h] ----------
__global__ __launch_bounds__(256) void mfma_out(
    const unsigned short* __restrict__ Plan, const unsigned short* __restrict__ TpT,
    const unsigned short* __restrict__ TarBf, float* __restrict__ Out) {
  const int b = blockIdx.z;
  const unsigned short* Ab = Plan + (size_t)b * Ln * Ln;   // [t][o], K=o
  const unsigned short* Bb = TpT + (size_t)b * Hn * Ln;    // [h][o], K=o
  const int row0 = blockIdx.y * 128;  // t
  const int col0 = blockIdx.x * 128;  // h
  MFMA_PROLOG(Ab, Bb, Ln)
#pragma unroll
  for (int m = 0; m < 4; ++m) {
#pragma unroll
    for (int n = 0; n < 4; ++n) {
      const int h = col0 + wc + n * 16 + cc;
#pragma unroll
      for (int r = 0; r < 4; ++r) {
        const int t = row0 + wr + m * 16 + cr + r;
        const size_t off = ((size_t)b * Ln + t) * Hn + h;
        Out[off] = acc[m][n][r] + bf2f(TarBf[off]);
      }
    }
  }
}

// ---------- r[row] = 1/max(||X_row||, eps), X bf16 [rows][1024] ----------
__global__ __launch_bounds__(256) void rownorm_bf16(
    const unsigned short* __restrict__ X, float* __restrict__ r, float eps) {
  const unsigned short* row = X + (size_t)blockIdx.x * Hn;
  const int i = threadIdx.x * 4;
  ushort4 v = *(const ushort4*)(row + i);
  float a0 = bf2f(v.x), a1 = bf2f(v.y), a2 = bf2f(v.z), a3 = bf2f(v.w);
  float s = block_reduce_sum(a0 * a0 + a1 * a1 + a2 * a2 + a3 * a3);
  if (threadIdx.x == 0) r[blockIdx.x] = 1.0f / fmaxf(sqrtf(s), eps);
}

// ---------- v = 1 ----------
__global__ __launch_bounds__(256) void init_ones(float* __restrict__ v) {
  v[blockIdx.x * 256 + threadIdx.x] = 1.0f;
}

// ---------- u[row] = 1 / dot(Q[row,:], v[b,:])  (one wave per row) ----------
__global__ __launch_bounds__(256) void u_step(
    const float* __restrict__ Q, const float* __restrict__ v, float* __restrict__ u) {
  const int row = blockIdx.x * 4 + (threadIdx.x >> 6);  // (b,t) flat
  const int b = row >> 9;
  const int lane = threadIdx.x & 63;
  const float* q = Q + (size_t)row * Ln;
  const float* vb = v + b * Ln;
  const float4 a = *(const float4*)(q + lane * 8);
  const float4 c = *(const float4*)(q + lane * 8 + 4);
  const float4 va = *(const float4*)(vb + lane * 8);
  const float4 vc = *(const float4*)(vb + lane * 8 + 4);
  float s = a.x * va.x + a.y * va.y + a.z * va.z + a.w * va.w +
            c.x * vc.x + c.y * vc.y + c.z * vc.z + c.w * vc.w;
#pragma unroll
  for (int off = 32; off > 0; off >>= 1) s += __shfl_down(s, off, 64);
  if (lane == 0) u[row] = 1.0f / s;
}

// ---------- v[b,o] = 1 / sum_t Q[b][t][o] * u[b,t] ----------
__global__ __launch_bounds__(256) void v_step(
    const float* __restrict__ Q, const float* __restrict__ u, float* __restrict__ v) {
  const int b = blockIdx.y;
  const float* Qb = Q + (size_t)b * Ln * Ln;
  __shared__ float us[Ln];
  us[threadIdx.x] = u[b * Ln + threadIdx.x];
  us[threadIdx.x + 256] = u[b * Ln + threadIdx.x + 256];
  __syncthreads();
  const int o = blockIdx.x * 256 + threadIdx.x;
  float s = 0.f;
#pragma unroll 4
  for (int t = 0; t < Ln; ++t) s += Qb[(size_t)t * Ln + o] * us[t];
  v[b * Ln + o] = 1.0f / s;
}

// ---------- plan_bf[row][o] = bf16( Q[row][o]*v[b,o] / max(||Q_row . v||, 1e-12) ) ----------
__global__ __launch_bounds__(256) void plan_prep(
    const float* __restrict__ Q, const float* __restrict__ v,
    unsigned short* __restrict__ P) {
  const int row = blockIdx.x;
  const int b = row >> 9;
  const float* q = Q + (size_t)row * Ln;
  const float* vb = v + b * Ln;
  const int i = threadIdx.x * 2;
  const float2 qq = *(const float2*)(q + i);
  const float2 vv = *(const float2*)(vb + i);
  const float p0 = qq.x * vv.x, p1 = qq.y * vv.y;
  const float s = block_reduce_sum(p0 * p0 + p1 * p1);
  const float rn = 1.0f / fmaxf(sqrtf(s), 1e-12f);
  ushort2 w;
  w.x = f2bf(p0 * rn);
  w.y = f2bf(p1 * rn);
  *(ushort2*)(P + (size_t)row * Ln + i) = w;
}

// ---------- LayerNorm over last dim, in-place ----------
__global__ __launch_bounds__(256) void ln_kernel(
    float* __restrict__ Out, const float* __restrict__ g, const float* __restrict__ b) {
  float* row = Out + (size_t)blockIdx.x * Hn;
  const int tid = threadIdx.x;
  float4 v = reinterpret_cast<float4*>(row)[tid];
  float s = v.x + v.y + v.z + v.w;
  float ss = v.x * v.x + v.y * v.y + v.z * v.z + v.w * v.w;
  const float tot = block_reduce_sum(s);
  const float tot2 = block_reduce_sum(ss);
  const float mu = tot * (1.0f / Hn);
  const float var = tot2 * (1.0f / Hn) - mu * mu;
  const float rs = rsqrtf(var + 1e-5f);
  const float4 gg = reinterpret_cast<const float4*>(g)[tid];
  const float4 bb = reinterpret_cast<const float4*>(b)[tid];
  v.x = (v.x - mu) * rs * gg.x + bb.x;
  v.y = (v.y - mu) * rs * gg.y + bb.y;
  v.z = (v.z - mu) * rs * gg.z + bb.z;
  v.w = (v.w - mu) * rs * gg.w + bb.w;
  reinterpret_cast<float4*>(row)[tid] = v;
}

extern "C" void kernel_launch(void* const* d_in, const int* in_sizes, int n_in,
                              void* d_out, int out_size, void* d_ws, size_t ws_size,
                              hipStream_t stream) {
  const float* origin = (const float*)d_in[0];
  const float* target = (const float*)d_in[1];
  const float* W_ori = (const float*)d_in[2];
  const float* b_ori = (const float*)d_in[3];
  const float* W_tar = (const float*)d_in[4];
  const float* b_tar = (const float*)d_in[5];
  const float* W_ft = (const float*)d_in[6];
  const float* b_ft = (const float*)d_in[7];
  const float* W_fo = (const float*)d_in[8];
  const float* b_fo = (const float*)d_in[9];
  const float* W_fot = (const float*)d_in[10];
  const float* b_fot = (const float*)d_in[11];
  const float* ln_g = (const float*)d_in[12];
  const float* ln_b = (const float*)d_in[13];
  float* out = (float*)d_out;

  // ---- workspace layout, ~82.1 MiB (lifetime-overlapped; all bf16 regions 16MiB) ----
  // [0,16M):   tar_bf            (GEMM3 -> mfma_out)
  // [16,32M):  P0 (origin/target staging) -> fc_bf (GEMM4 -> cos)
  // [32,48M):  P1 (t1 staging)   -> tp_bf (GEMM5 -> transpose) -> plan_bf (8M)
  // [48,64M):  ori_bf (GEMM1..5) -> Q f32 (cos -> plan_prep)
  // [64,80M):  tpT               (transpose -> mfma_out)
  // [80,82M):  Wt (serially reused transposed weight)
  // [82M..):   rt, rf, u, v      (4 x 32KB)
  char* ws = (char*)d_ws;
  const size_t MB = 1048576;
  unsigned short* tar_bf = (unsigned short*)(ws + 0);
  unsigned short* P0 = (unsigned short*)(ws + 16 * MB);
  unsigned short* fc_bf = (unsigned short*)(ws + 16 * MB);
  unsigned short* P1 = (unsigned short*)(ws + 32 * MB);
  unsigned short* tp_bf = (unsigned short*)(ws + 32 * MB);
  unsigned short* plan_bf = (unsigned short*)(ws + 32 * MB);
  unsigned short* ori_bf = (unsigned short*)(ws + 48 * MB);
  float* Qw = (float*)(ws + 48 * MB);
  unsigned short* tpT = (unsigned short*)(ws + 64 * MB);
  unsigned short* Wt = (unsigned short*)(ws + 80 * MB);
  float* rt = (float*)(ws + 82 * MB);
  float* rf = rt + RowsT;
  float* uu = rf + RowsT;
  float* vv = uu + RowsT;

  const dim3 blk(256);
  const dim3 gConv(RowsT * Hn / (256 * 8));
  const dim3 gTrW(Hn / 32, Hn / 32);
  const dim3 gMM(Hn / 128, RowsT / 128);            // (8,64)
  const dim3 gCos(Ln / 128, Ln / 128, Bn);          // (4,4,16)
  const dim3 gOut(Hn / 128, Ln / 128, Bn);          // (8,4,16)
  const dim3 gTrA(Hn / 32, Ln / 32, Bn);            // (32,16,16)

  // ori = origin @ W_ori + b_ori
  f32_to_bf16_kernel<<<gConv, blk, 0, stream>>>(origin, P0);
  transpose_w_bf16<<<gTrW, blk, 0, stream>>>(W_ori, Wt, Hn, Hn);
  mfma_gemm_bias<<<gMM, blk, 0, stream>>>(P0, Wt, b_ori, ori_bf, Hn, Hn);
  // t1 = target @ W_tar + b_tar
  f32_to_bf16_kernel<<<gConv, blk, 0, stream>>>(target, P0);
  transpose_w_bf16<<<gTrW, blk, 0, stream>>>(W_tar, Wt, Hn, Hn);
  mfma_gemm_bias<<<gMM, blk, 0, stream>>>(P0, Wt, b_tar, P1, Hn, Hn);
  // tar = t1 @ W_ft + b_ft
  transpose_w_bf16<<<gTrW, blk, 0, stream>>>(W_ft, Wt, Hn, Hn);
  mfma_gemm_bias<<<gMM, blk, 0, stream>>>(P1, Wt, b_ft, tar_bf, Hn, Hn);
  // fc = ori @ W_fo + b_fo
  transpose_w_bf16<<<gTrW, blk, 0, stream>>>(W_fo, Wt, Hn, Hn);
  mfma_gemm_bias<<<gMM, blk, 0, stream>>>(ori_bf, Wt, b_fo, fc_bf, Hn, Hn);
  // tp = ori @ W_fot + b_fot
  transpose_w_bf16<<<gTrW, blk, 0, stream>>>(W_fot, Wt, Hn, Hn);
  mfma_gemm_bias<<<gMM, blk, 0, stream>>>(ori_bf, Wt, b_fot, tp_bf, Hn, Hn);
  // tpT[b][h][o] = tp[b][o][h]
  transpose_act_bf16<<<gTrA, blk, 0, stream>>>(tp_bf, tpT);

  // cosine norms from the bf16 vectors (exact unit-norm of quantized vectors)
  rownorm_bf16<<<dim3(RowsT), blk, 0, stream>>>(tar_bf, rt, 1e-8f);
  rownorm_bf16<<<dim3(RowsT), blk, 0, stream>>>(fc_bf, rf, 1e-8f);

  // Q = exp(cos/0.05)  (overwrites dead ori_bf)
  mfma_cos_exp<<<gCos, blk, 0, stream>>>(tar_bf, fc_bf, rt, rf, Qw);

  // Sinkhorn via scaling vectors: u = 1/(Q v); v = 1/(Q^T u)
  init_ones<<<dim3(RowsT / 256), blk, 0, stream>>>(vv);
  for (int it = 0; it < 5; ++it) {
    u_step<<<dim3(RowsT / 4), blk, 0, stream>>>(Qw, vv, uu);
    v_step<<<dim3(Ln / 256, Bn), blk, 0, stream>>>(Qw, uu, vv);
  }
  // plan = l2norm_row(Q . v) -> bf16 (u cancels in the row normalization)
  plan_prep<<<dim3(RowsT), blk, 0, stream>>>(Qw, vv, plan_bf);

  // out = plan @ tp + tar
  mfma_out<<<gOut, blk, 0, stream>>>(plan_bf, tpT, tar_bf, out);

  // LayerNorm in-place
  ln_kernel<<<dim3(RowsT), blk, 0, stream>>>(out, ln_g, ln_b);
}

// Round 5
// 487.932 us; speedup vs baseline: 2.0383x; 1.1117x over previous
//
#include <hip/hip_runtime.h>
#include <hip/hip_bf16.h>
#include <math.h>

// Problem constants
constexpr int Bn = 16;
constexpr int Ln = 512;
constexpr int Hn = 1024;
constexpr int RowsT = Bn * Ln;  // 8192

typedef __attribute__((ext_vector_type(8))) short bf16x8;
typedef __attribute__((ext_vector_type(4))) float f32x4;
typedef __attribute__((ext_vector_type(8))) unsigned short u16x8;

__device__ __forceinline__ unsigned short f2bf(float f) {  // RNE f32->bf16
  unsigned u = __float_as_uint(f);
  u += 0x7FFFu + ((u >> 16) & 1u);
  return (unsigned short)(u >> 16);
}
__device__ __forceinline__ float bf2f(unsigned short u) {
  return __uint_as_float(((unsigned)u) << 16);
}

__device__ __forceinline__ void gload_lds16(const void* g, void* l) {
  __builtin_amdgcn_global_load_lds(
      (const __attribute__((address_space(1))) void*)g,
      (__attribute__((address_space(3))) void*)l, 16, 0, 0);
}

// ---------------- block-wide reduction ----------------
__device__ __forceinline__ float block_reduce_sum(float v) {
  __shared__ float sbuf[8];
  const int lane = threadIdx.x & 63;
  const int wid = threadIdx.x >> 6;
#pragma unroll
  for (int off = 32; off > 0; off >>= 1) v += __shfl_down(v, off, 64);
  __syncthreads();
  if (lane == 0) sbuf[wid] = v;
  __syncthreads();
  if (threadIdx.x == 0) {
    float t = 0.f;
    const int nw = (blockDim.x + 63) >> 6;
    for (int i = 0; i < nw; ++i) t += sbuf[i];
    sbuf[0] = t;
  }
  __syncthreads();
  return sbuf[0];
}

// ---------- f32 -> bf16, z-batched (8 elems/thread) ----------
__global__ __launch_bounds__(256) void conv_z(
    const float* __restrict__ s0, const float* __restrict__ s1,
    unsigned short* __restrict__ d0, unsigned short* __restrict__ d1) {
  const float* in = blockIdx.z ? s1 : s0;
  unsigned short* out = blockIdx.z ? d1 : d0;
  const size_t i = ((size_t)blockIdx.x * blockDim.x + threadIdx.x) * 8;
  const float4 a = *(const float4*)(in + i);
  const float4 b = *(const float4*)(in + i + 4);
  u16x8 r;
  r[0] = f2bf(a.x); r[1] = f2bf(a.y); r[2] = f2bf(a.z); r[3] = f2bf(a.w);
  r[4] = f2bf(b.x); r[5] = f2bf(b.y); r[6] = f2bf(b.z); r[7] = f2bf(b.w);
  *(u16x8*)(out + i) = r;
}

// ---------- W[K][N] f32 -> Wt[N][K] bf16, z-batched ----------
__global__ __launch_bounds__(256) void transpose_w_z(
    const float* __restrict__ s0, const float* __restrict__ s1,
    unsigned short* __restrict__ d0, unsigned short* __restrict__ d1,
    int K, int N) {
  const float* W = blockIdx.z ? s1 : s0;
  unsigned short* Wt = blockIdx.z ? d1 : d0;
  __shared__ float t[32][33];
  const int n0 = blockIdx.x * 32;
  const int k0 = blockIdx.y * 32;
  const int tx = threadIdx.x & 31;
  const int ty = threadIdx.x >> 5;
#pragma unroll
  for (int i = 0; i < 32; i += 8)
    t[ty + i][tx] = W[(size_t)(k0 + ty + i) * N + n0 + tx];
  __syncthreads();
#pragma unroll
  for (int i = 0; i < 32; i += 8)
    Wt[(size_t)(n0 + ty + i) * K + k0 + tx] = f2bf(t[tx][ty + i]);
}

// ---------- bc[n] = sum_j b1[j]*W[j][n] + b2[n], z-batched (3) ----------
__global__ __launch_bounds__(256) void bias_combine(
    const float* __restrict__ b1a, const float* __restrict__ Wa, const float* __restrict__ b2a,
    const float* __restrict__ b1b, const float* __restrict__ Wb, const float* __restrict__ b2b,
    const float* __restrict__ b1c, const float* __restrict__ Wc, const float* __restrict__ b2c,
    float* __restrict__ o0, float* __restrict__ o1, float* __restrict__ o2) {
  const int z = blockIdx.y;
  const float* b1 = z == 0 ? b1a : (z == 1 ? b1b : b1c);
  const float* W  = z == 0 ? Wa  : (z == 1 ? Wb  : Wc);
  const float* b2 = z == 0 ? b2a : (z == 1 ? b2b : b2c);
  float* out      = z == 0 ? o0  : (z == 1 ? o1  : o2);
  const int n = blockIdx.x * 256 + threadIdx.x;
  float s = b2[n];
  for (int j = 0; j < Hn; ++j) s += b1[j] * W[(size_t)j * Hn + n];
  out[n] = s;
}

// ================= MFMA GEMM core (m97 structure: 128x128, BK=32) =================
#define MFMA_PROLOG(Aptr, Bptr, Kdim)                                          \
  constexpr int BK = 32;                                                       \
  __shared__ unsigned short As[128][BK];                                       \
  __shared__ unsigned short Bs[128][BK];                                       \
  const int tid = threadIdx.x;                                                 \
  const int wid = tid >> 6;                                                    \
  const int lane = tid & 63;                                                   \
  const int wr = (wid >> 1) * 64;                                              \
  const int wc = (wid & 1) * 64;                                               \
  const int sr = lane >> 2;                                                    \
  const int sk = (lane & 3) * 8;                                               \
  const size_t arow = (size_t)(row0 + wid * 32 + sr) * Kdim + sk;              \
  const size_t brow = (size_t)(col0 + wid * 32 + sr) * Kdim + sk;              \
  f32x4 acc[4][4] = {};                                                        \
  for (int k0 = 0; k0 < Kdim; k0 += BK) {                                      \
    gload_lds16(Aptr + arow + k0,                      &As[wid * 32][0]);      \
    gload_lds16(Aptr + arow + (size_t)16 * Kdim + k0,  &As[wid * 32 + 16][0]); \
    gload_lds16(Bptr + brow + k0,                      &Bs[wid * 32][0]);      \
    gload_lds16(Bptr + brow + (size_t)16 * Kdim + k0,  &Bs[wid * 32 + 16][0]); \
    __syncthreads();                                                           \
    bf16x8 af[4], bfr[4];                                                      \
    _Pragma("unroll")                                                          \
    for (int m = 0; m < 4; ++m)                                                \
      af[m] = *(const bf16x8*)&As[wr + m * 16 + (lane & 15)][(lane >> 4) * 8]; \
    _Pragma("unroll")                                                          \
    for (int n = 0; n < 4; ++n)                                                \
      bfr[n] = *(const bf16x8*)&Bs[wc + n * 16 + (lane & 15)][(lane >> 4) * 8];\
    _Pragma("unroll")                                                          \
    for (int m = 0; m < 4; ++m)                                                \
      _Pragma("unroll")                                                        \
      for (int n = 0; n < 4; ++n)                                              \
        acc[m][n] = __builtin_amdgcn_mfma_f32_16x16x32_bf16(af[m], bfr[n],     \
                                                            acc[m][n], 0, 0, 0);\
    __syncthreads();                                                           \
  }                                                                            \
  const int cr = (lane >> 4) * 4;                                              \
  const int cc = lane & 15;

// ---------- z-batched GEMM: D = A @ Bt^T (+bias), bf16 out ----------
// mode 0: D row-major [M][N].  mode 1: rows are (b,o) flat, write D[b][col][o] (tpT).
__global__ __launch_bounds__(256) void mfma_gemm_z(
    const unsigned short* __restrict__ A0, const unsigned short* __restrict__ A1,
    const unsigned short* __restrict__ Bt0, const unsigned short* __restrict__ Bt1,
    const float* __restrict__ bias0, const float* __restrict__ bias1,
    unsigned short* __restrict__ D0, unsigned short* __restrict__ D1,
    int mode1, int N, int K) {
  const int z = blockIdx.z;
  const unsigned short* A = z ? A1 : A0;
  const unsigned short* Bt = z ? Bt1 : Bt0;
  const float* bias = z ? bias1 : bias0;
  unsigned short* D = z ? D1 : D0;
  const int mode = z ? mode1 : 0;
  const int row0 = blockIdx.y * 128;
  const int col0 = blockIdx.x * 128;
  MFMA_PROLOG(A, Bt, K)
  if (mode == 0) {
#pragma unroll
    for (int m = 0; m < 4; ++m) {
#pragma unroll
      for (int n = 0; n < 4; ++n) {
        const int gc = col0 + wc + n * 16 + cc;
        const float bv = bias ? bias[gc] : 0.f;
#pragma unroll
        for (int r = 0; r < 4; ++r) {
          const int gr = row0 + wr + m * 16 + cr + r;
          D[(size_t)gr * N + gc] = f2bf(acc[m][n][r] + bv);
        }
      }
    }
  } else {
    // transposed write: gr = b*512 + o; store D[(b*Hn+gc)*Ln + o], 4 o's packed
#pragma unroll
    for (int m = 0; m < 4; ++m) {
      const int gr0 = row0 + wr + m * 16 + cr;   // o-contiguous base (mult of 4)
      const int b = gr0 >> 9;
      const int o = gr0 & 511;
#pragma unroll
      for (int n = 0; n < 4; ++n) {
        const int gc = col0 + wc + n * 16 + cc;
        const float bv = bias ? bias[gc] : 0.f;
        ushort4 w;
        w.x = f2bf(acc[m][n][0] + bv);
        w.y = f2bf(acc[m][n][1] + bv);
        w.z = f2bf(acc[m][n][2] + bv);
        w.w = f2bf(acc[m][n][3] + bv);
        *(ushort4*)(D + ((size_t)b * Hn + gc) * Ln + o) = w;
      }
    }
  }
}

// ---------- Q[b][t][o] = exp(20 * <tar_t, fc_o> * rt[b,t] * rf[b,o]) ----------
__global__ __launch_bounds__(256) void mfma_cos_exp(
    const unsigned short* __restrict__ TarBf, const unsigned short* __restrict__ FcBf,
    const float* __restrict__ rt, const float* __restrict__ rf,
    float* __restrict__ Q) {
  const int b = blockIdx.z;
  const unsigned short* Ab = TarBf + (size_t)b * Ln * Hn;
  const unsigned short* Bb = FcBf + (size_t)b * Ln * Hn;
  float* Qb = Q + (size_t)b * Ln * Ln;
  const int row0 = blockIdx.y * 128;  // t
  const int col0 = blockIdx.x * 128;  // o
  MFMA_PROLOG(Ab, Bb, Hn)
#pragma unroll
  for (int m = 0; m < 4; ++m) {
#pragma unroll
    for (int n = 0; n < 4; ++n) {
      const int o = col0 + wc + n * 16 + cc;
      const float rfo = rf[b * Ln + o] * 20.0f;
#pragma unroll
      for (int r = 0; r < 4; ++r) {
        const int t = row0 + wr + m * 16 + cr + r;
        const float c = acc[m][n][r] * rt[b * Ln + t] * rfo;
        Qb[(size_t)t * Ln + o] = __expf(c);
      }
    }
  }
}

// ---------- Out[b][t][h] = plan[b][t][:] @ tpT[b][h][:]^T + tar[b][t][h] ----------
__global__ __launch_bounds__(256) void mfma_out(
    const unsigned short* __restrict__ Plan, const unsigned short* __restrict__ TpT,
    const unsigned short* __restrict__ TarBf, float* __restrict__ Out) {
  const int b = blockIdx.z;
  const unsigned short* Ab = Plan + (size_t)b * Ln * Ln;
  const unsigned short* Bb = TpT + (size_t)b * Hn * Ln;
  const int row0 = blockIdx.y * 128;  // t
  const int col0 = blockIdx.x * 128;  // h
  MFMA_PROLOG(Ab, Bb, Ln)
#pragma unroll
  for (int m = 0; m < 4; ++m) {
#pragma unroll
    for (int n = 0; n < 4; ++n) {
      const int h = col0 + wc + n * 16 + cc;
#pragma unroll
      for (int r = 0; r < 4; ++r) {
        const int t = row0 + wr + m * 16 + cr + r;
        const size_t off = ((size_t)b * Ln + t) * Hn + h;
        Out[off] = acc[m][n][r] + bf2f(TarBf[off]);
      }
    }
  }
}

// ---------- r[row] = 1/max(||X_row||, eps), z-batched ----------
__global__ __launch_bounds__(256) void rownorm_z(
    const unsigned short* __restrict__ X0, const unsigned short* __restrict__ X1,
    float* __restrict__ r0, float* __restrict__ r1, float eps) {
  const unsigned short* X = blockIdx.y ? X1 : X0;
  float* r = blockIdx.y ? r1 : r0;
  const unsigned short* row = X + (size_t)blockIdx.x * Hn;
  const int i = threadIdx.x * 4;
  ushort4 v = *(const ushort4*)(row + i);
  float a0 = bf2f(v.x), a1 = bf2f(v.y), a2 = bf2f(v.z), a3 = bf2f(v.w);
  float s = block_reduce_sum(a0 * a0 + a1 * a1 + a2 * a2 + a3 * a3);
  if (threadIdx.x == 0) r[blockIdx.x] = 1.0f / fmaxf(sqrtf(s), eps);
}

// ---------- u[row] = 1 / dot(Q[row,:], v[b,:])  (one wave per row) ----------
template<bool FIRST>
__global__ __launch_bounds__(256) void u_step(
    const float* __restrict__ Q, const float* __restrict__ v, float* __restrict__ u) {
  const int row = blockIdx.x * 4 + (threadIdx.x >> 6);
  const int b = row >> 9;
  const int lane = threadIdx.x & 63;
  const float* q = Q + (size_t)row * Ln;
  const float4 a = *(const float4*)(q + lane * 8);
  const float4 c = *(const float4*)(q + lane * 8 + 4);
  float s;
  if (FIRST) {
    s = a.x + a.y + a.z + a.w + c.x + c.y + c.z + c.w;
  } else {
    const float* vb = v + b * Ln;
    const float4 va = *(const float4*)(vb + lane * 8);
    const float4 vc = *(const float4*)(vb + lane * 8 + 4);
    s = a.x * va.x + a.y * va.y + a.z * va.z + a.w * va.w +
        c.x * vc.x + c.y * vc.y + c.z * vc.z + c.w * vc.w;
  }
#pragma unroll
  for (int off = 32; off > 0; off >>= 1) s += __shfl_down(s, off, 64);
  if (lane == 0) u[row] = 1.0f / s;
}

// ---------- v[b,o] = 1 / sum_t Q[b][t][o]*u[b,t]   (128 blocks) ----------
__global__ __launch_bounds__(256) void v_step(
    const float* __restrict__ Q, const float* __restrict__ u, float* __restrict__ v) {
  const int b = blockIdx.y;
  const float* Qb = Q + (size_t)b * Ln * Ln;
  __shared__ float us[Ln];
  __shared__ float part[4][64];
  const int tid = threadIdx.x;
  us[tid] = u[b * Ln + tid];
  us[tid + 256] = u[b * Ln + tid + 256];
  __syncthreads();
  const int c = tid & 63;
  const int chunk = tid >> 6;
  const int o = blockIdx.x * 64 + c;
  float s = 0.f;
#pragma unroll 4
  for (int t = chunk * 128; t < chunk * 128 + 128; ++t)
    s += Qb[(size_t)t * Ln + o] * us[t];
  part[chunk][c] = s;
  __syncthreads();
  if (chunk == 0)
    v[b * Ln + o] = 1.0f / (part[0][c] + part[1][c] + part[2][c] + part[3][c]);
}

// ---------- plan_bf = bf16( Q.v / max(||row(Q.v)||, 1e-12) ) ----------
__global__ __launch_bounds__(256) void plan_prep(
    const float* __restrict__ Q, const float* __restrict__ v,
    unsigned short* __restrict__ P) {
  const int row = blockIdx.x;
  const int b = row >> 9;
  const float* q = Q + (size_t)row * Ln;
  const float* vb = v + b * Ln;
  const int i = threadIdx.x * 2;
  const float2 qq = *(const float2*)(q + i);
  const float2 vv = *(const float2*)(vb + i);
  const float p0 = qq.x * vv.x, p1 = qq.y * vv.y;
  const float s = block_reduce_sum(p0 * p0 + p1 * p1);
  const float rn = 1.0f / fmaxf(sqrtf(s), 1e-12f);
  ushort2 w;
  w.x = f2bf(p0 * rn);
  w.y = f2bf(p1 * rn);
  *(ushort2*)(P + (size_t)row * Ln + i) = w;
}

// ---------- LayerNorm over last dim, in-place ----------
__global__ __launch_bounds__(256) void ln_kernel(
    float* __restrict__ Out, const float* __restrict__ g, const float* __restrict__ b) {
  float* row = Out + (size_t)blockIdx.x * Hn;
  const int tid = threadIdx.x;
  float4 v = reinterpret_cast<float4*>(row)[tid];
  float s = v.x + v.y + v.z + v.w;
  float ss = v.x * v.x + v.y * v.y + v.z * v.z + v.w * v.w;
  const float tot = block_reduce_sum(s);
  const float tot2 = block_reduce_sum(ss);
  const float mu = tot * (1.0f / Hn);
  const float var = tot2 * (1.0f / Hn) - mu * mu;
  const float rs = rsqrtf(var + 1e-5f);
  const float4 gg = reinterpret_cast<const float4*>(g)[tid];
  const float4 bb = reinterpret_cast<const float4*>(b)[tid];
  v.x = (v.x - mu) * rs * gg.x + bb.x;
  v.y = (v.y - mu) * rs * gg.y + bb.y;
  v.z = (v.z - mu) * rs * gg.z + bb.z;
  v.w = (v.w - mu) * rs * gg.w + bb.w;
  reinterpret_cast<float4*>(row)[tid] = v;
}

extern "C" void kernel_launch(void* const* d_in, const int* in_sizes, int n_in,
                              void* d_out, int out_size, void* d_ws, size_t ws_size,
                              hipStream_t stream) {
  const float* origin = (const float*)d_in[0];
  const float* target = (const float*)d_in[1];
  const float* W_ori = (const float*)d_in[2];
  const float* b_ori = (const float*)d_in[3];
  const float* W_tar = (const float*)d_in[4];
  const float* b_tar = (const float*)d_in[5];
  const float* W_ft = (const float*)d_in[6];
  const float* b_ft = (const float*)d_in[7];
  const float* W_fo = (const float*)d_in[8];
  const float* b_fo = (const float*)d_in[9];
  const float* W_fot = (const float*)d_in[10];
  const float* b_fot = (const float*)d_in[11];
  const float* ln_g = (const float*)d_in[12];
  const float* ln_b = (const float*)d_in[13];
  float* out = (float*)d_out;

  // ---- workspace layout, 80 MiB + 140 KiB (lifetime-overlapped) ----
  // [0,16M):  O_bf (origin bf16; ->bigGEMM-2)      -> Q f32 (cos -> plan_prep)
  // [16,32M): T_bf (target bf16; ->bigGEMM-1)      -> Wori_bf@16,WfoT@18,WfotT@20,
  //           Wc2T@22,Wc3T@24 (->bigGEMM-2)        -> plan_bf@[16,24M)
  // [32,48M): Wtar_bf@32,WftT@34 (->combine-1)     -> tar_bf (bigGEMM-1 -> end)
  // [48,64M): Wc1T@48 (->bigGEMM-1)                -> fc_bf (bigGEMM-2 -> cos)
  // [64,80M): tpT (bigGEMM-2, transposed-write -> mfma_out)
  // [80M..):  bc1,bc2,bc3 (4KB each), rt,rf,u,v (32KB each)
  char* ws = (char*)d_ws;
  const size_t MB = 1048576;
  unsigned short* O_bf = (unsigned short*)(ws + 0);
  float* Qw = (float*)(ws + 0);
  unsigned short* T_bf = (unsigned short*)(ws + 16 * MB);
  unsigned short* Wori_bf = (unsigned short*)(ws + 16 * MB);
  unsigned short* WfoT = (unsigned short*)(ws + 18 * MB);
  unsigned short* WfotT = (unsigned short*)(ws + 20 * MB);
  unsigned short* Wc2T = (unsigned short*)(ws + 22 * MB);
  unsigned short* Wc3T = (unsigned short*)(ws + 24 * MB);
  unsigned short* plan_bf = (unsigned short*)(ws + 16 * MB);
  unsigned short* Wtar_bf = (unsigned short*)(ws + 32 * MB);
  unsigned short* WftT = (unsigned short*)(ws + 34 * MB);
  unsigned short* tar_bf = (unsigned short*)(ws + 32 * MB);
  unsigned short* Wc1T = (unsigned short*)(ws + 48 * MB);
  unsigned short* fc_bf = (unsigned short*)(ws + 48 * MB);
  unsigned short* tpT = (unsigned short*)(ws + 64 * MB);
  float* bc1 = (float*)(ws + 80 * MB);
  float* bc2 = bc1 + 1024;
  float* bc3 = bc2 + 1024;
  float* rt = bc3 + 1024;
  float* rf = rt + RowsT;
  float* uu = rf + RowsT;
  float* vv = uu + RowsT;

  const dim3 blk(256);

  // 1) quantize origin, target -> bf16
  conv_z<<<dim3(RowsT * Hn / 2048, 1, 2), blk, 0, stream>>>(origin, target, O_bf, T_bf);
  // 2) quantize W_tar; 3) transpose W_ft  (temps in tar region, dead at bigGEMM-1)
  conv_z<<<dim3(Hn * Hn / 2048, 1, 1), blk, 0, stream>>>(W_tar, W_tar, Wtar_bf, Wtar_bf);
  transpose_w_z<<<dim3(32, 32, 1), blk, 0, stream>>>(W_ft, W_ft, WftT, WftT, Hn, Hn);
  // 4) combined biases: bc1=b_tar@W_ft+b_ft; bc2=b_ori@W_fo+b_fo; bc3=b_ori@W_fot+b_fot
  bias_combine<<<dim3(4, 3), blk, 0, stream>>>(b_tar, W_ft, b_ft, b_ori, W_fo, b_fo,
                                               b_ori, W_fot, b_fot, bc1, bc2, bc3);
  // 5) Wc1^T = W_ft^T @ W_tar^T   (A=WftT, Bt=Wtar_bf)
  mfma_gemm_z<<<dim3(8, 8, 1), blk, 0, stream>>>(WftT, WftT, Wtar_bf, Wtar_bf,
                                                 nullptr, nullptr, Wc1T, Wc1T, 0, Hn, Hn);
  // 6) tar = target @ Wc1 + bc1   (T_bf, Wtar/WftT die; tar written over them)
  mfma_gemm_z<<<dim3(8, 64, 1), blk, 0, stream>>>(T_bf, T_bf, Wc1T, Wc1T,
                                                  bc1, bc1, tar_bf, tar_bf, 0, Hn, Hn);
  // 7) quantize W_ori; 8) transpose W_fo, W_fot (temps in dead T region)
  conv_z<<<dim3(Hn * Hn / 2048, 1, 1), blk, 0, stream>>>(W_ori, W_ori, Wori_bf, Wori_bf);
  transpose_w_z<<<dim3(32, 32, 2), blk, 0, stream>>>(W_fo, W_fot, WfoT, WfotT, Hn, Hn);
  // 9) Wc2^T = W_fo^T @ W_ori^T ; Wc3^T = W_fot^T @ W_ori^T
  mfma_gemm_z<<<dim3(8, 8, 2), blk, 0, stream>>>(WfoT, WfotT, Wori_bf, Wori_bf,
                                                 nullptr, nullptr, Wc2T, Wc3T, 0, Hn, Hn);
  // 10) fc = origin@Wc2+bc2 (row-major); tpT = transpose(origin@Wc3+bc3) (mode1)
  mfma_gemm_z<<<dim3(8, 64, 2), blk, 0, stream>>>(O_bf, O_bf, Wc2T, Wc3T,
                                                  bc2, bc3, fc_bf, tpT, 1, Hn, Hn);
  // 11) cosine norms
  rownorm_z<<<dim3(RowsT, 2), blk, 0, stream>>>(tar_bf, fc_bf, rt, rf, 1e-8f);
  // 12) Q = exp(cos/0.05)  (into dead O region)
  mfma_cos_exp<<<dim3(4, 4, Bn), blk, 0, stream>>>(tar_bf, fc_bf, rt, rf, Qw);
  // 13..22) Sinkhorn: u = 1/(Qv); v = 1/(Q^T u); first u has v==1
  u_step<true><<<dim3(RowsT / 4), blk, 0, stream>>>(Qw, vv, uu);
  v_step<<<dim3(Ln / 64, Bn), blk, 0, stream>>>(Qw, uu, vv);
  for (int it = 1; it < 5; ++it) {
    u_step<false><<<dim3(RowsT / 4), blk, 0, stream>>>(Qw, vv, uu);
    v_step<<<dim3(Ln / 64, Bn), blk, 0, stream>>>(Qw, uu, vv);
  }
  // 23) plan = l2norm_row(Q.v) -> bf16 (u cancels)
  plan_prep<<<dim3(RowsT), blk, 0, stream>>>(Qw, vv, plan_bf);
  // 24) out = plan @ tp + tar
  mfma_out<<<dim3(Hn / 128, Ln / 128, Bn), blk, 0, stream>>>(plan_bf, tpT, tar_bf, out);
  // 25) LayerNorm in-place
  ln_kernel<<<dim3(RowsT), blk, 0, stream>>>(out, ln_g, ln_b);
}

// Round 6
// 479.628 us; speedup vs baseline: 2.0736x; 1.0173x over previous
//
#include <hip/hip_runtime.h>
#include <hip/hip_bf16.h>
#include <math.h>

// Problem constants
constexpr int Bn = 16;
constexpr int Ln = 512;
constexpr int Hn = 1024;
constexpr int RowsT = Bn * Ln;  // 8192

typedef __attribute__((ext_vector_type(8))) short bf16x8;
typedef __attribute__((ext_vector_type(4))) float f32x4;
typedef __attribute__((ext_vector_type(8))) unsigned short u16x8;

__device__ __forceinline__ unsigned short f2bf(float f) {  // RNE f32->bf16
  unsigned u = __float_as_uint(f);
  u += 0x7FFFu + ((u >> 16) & 1u);
  return (unsigned short)(u >> 16);
}
__device__ __forceinline__ float bf2f(unsigned short u) {
  return __uint_as_float(((unsigned)u) << 16);
}

__device__ __forceinline__ void gload_lds16(const void* g, void* l) {
  __builtin_amdgcn_global_load_lds(
      (const __attribute__((address_space(1))) void*)g,
      (__attribute__((address_space(3))) void*)l, 16, 0, 0);
}

// ---------------- block-wide reduction (256 threads) ----------------
__device__ __forceinline__ float block_reduce_sum(float v) {
  __shared__ float sbuf[8];
  const int lane = threadIdx.x & 63;
  const int wid = threadIdx.x >> 6;
#pragma unroll
  for (int off = 32; off > 0; off >>= 1) v += __shfl_down(v, off, 64);
  __syncthreads();
  if (lane == 0) sbuf[wid] = v;
  __syncthreads();
  if (threadIdx.x == 0) {
    float t = 0.f;
    const int nw = (blockDim.x + 63) >> 6;
    for (int i = 0; i < nw; ++i) t += sbuf[i];
    sbuf[0] = t;
  }
  __syncthreads();
  return sbuf[0];
}

// ---------- f32 -> bf16, z-batched (8 elems/thread) ----------
__global__ __launch_bounds__(256) void conv_z(
    const float* __restrict__ s0, const float* __restrict__ s1,
    unsigned short* __restrict__ d0, unsigned short* __restrict__ d1) {
  const float* in = blockIdx.z ? s1 : s0;
  unsigned short* out = blockIdx.z ? d1 : d0;
  const size_t i = ((size_t)blockIdx.x * blockDim.x + threadIdx.x) * 8;
  const float4 a = *(const float4*)(in + i);
  const float4 b = *(const float4*)(in + i + 4);
  u16x8 r;
  r[0] = f2bf(a.x); r[1] = f2bf(a.y); r[2] = f2bf(a.z); r[3] = f2bf(a.w);
  r[4] = f2bf(b.x); r[5] = f2bf(b.y); r[6] = f2bf(b.z); r[7] = f2bf(b.w);
  *(u16x8*)(out + i) = r;
}

// ---------- W[K][N] f32 -> Wt[N][K] bf16, 3-way z ----------
__global__ __launch_bounds__(256) void transpose_w3(
    const float* __restrict__ s0, const float* __restrict__ s1, const float* __restrict__ s2,
    unsigned short* __restrict__ d0, unsigned short* __restrict__ d1,
    unsigned short* __restrict__ d2, int K, int N) {
  const int z = blockIdx.z;
  const float* W = z == 0 ? s0 : (z == 1 ? s1 : s2);
  unsigned short* Wt = z == 0 ? d0 : (z == 1 ? d1 : d2);
  __shared__ float t[32][33];
  const int n0 = blockIdx.x * 32;
  const int k0 = blockIdx.y * 32;
  const int tx = threadIdx.x & 31;
  const int ty = threadIdx.x >> 5;
#pragma unroll
  for (int i = 0; i < 32; i += 8)
    t[ty + i][tx] = W[(size_t)(k0 + ty + i) * N + n0 + tx];
  __syncthreads();
#pragma unroll
  for (int i = 0; i < 32; i += 8)
    Wt[(size_t)(n0 + ty + i) * K + k0 + tx] = f2bf(t[tx][ty + i]);
}

// ---------- bc[n] = sum_j b1[j]*W[j][n] + b2[n], z-batched (3) ----------
__global__ __launch_bounds__(256) void bias_combine(
    const float* __restrict__ b1a, const float* __restrict__ Wa, const float* __restrict__ b2a,
    const float* __restrict__ b1b, const float* __restrict__ Wb, const float* __restrict__ b2b,
    const float* __restrict__ b1c, const float* __restrict__ Wc, const float* __restrict__ b2c,
    float* __restrict__ o0, float* __restrict__ o1, float* __restrict__ o2) {
  const int z = blockIdx.y;
  const float* b1 = z == 0 ? b1a : (z == 1 ? b1b : b1c);
  const float* W  = z == 0 ? Wa  : (z == 1 ? Wb  : Wc);
  const float* b2 = z == 0 ? b2a : (z == 1 ? b2b : b2c);
  float* out      = z == 0 ? o0  : (z == 1 ? o1  : o2);
  const int n = blockIdx.x * 256 + threadIdx.x;
  float s = b2[n];
  for (int j = 0; j < Hn; ++j) s += b1[j] * W[(size_t)j * Hn + n];
  out[n] = s;
}

// ================= MFMA GEMM core (m97 structure: 128x128, BK=32) =================
#define MFMA_PROLOG(Aptr, Bptr, Kdim)                                          \
  constexpr int BK = 32;                                                       \
  __shared__ unsigned short As[128][BK];                                       \
  __shared__ unsigned short Bs[128][BK];                                       \
  const int tid = threadIdx.x;                                                 \
  const int wid = tid >> 6;                                                    \
  const int lane = tid & 63;                                                   \
  const int wr = (wid >> 1) * 64;                                              \
  const int wc = (wid & 1) * 64;                                               \
  const int sr = lane >> 2;                                                    \
  const int sk = (lane & 3) * 8;                                               \
  const size_t arow = (size_t)(row0 + wid * 32 + sr) * Kdim + sk;              \
  const size_t brow = (size_t)(col0 + wid * 32 + sr) * Kdim + sk;              \
  f32x4 acc[4][4] = {};                                                        \
  for (int k0 = 0; k0 < Kdim; k0 += BK) {                                      \
    gload_lds16(Aptr + arow + k0,                      &As[wid * 32][0]);      \
    gload_lds16(Aptr + arow + (size_t)16 * Kdim + k0,  &As[wid * 32 + 16][0]); \
    gload_lds16(Bptr + brow + k0,                      &Bs[wid * 32][0]);      \
    gload_lds16(Bptr + brow + (size_t)16 * Kdim + k0,  &Bs[wid * 32 + 16][0]); \
    __syncthreads();                                                           \
    bf16x8 af[4], bfr[4];                                                      \
    _Pragma("unroll")                                                          \
    for (int m = 0; m < 4; ++m)                                                \
      af[m] = *(const bf16x8*)&As[wr + m * 16 + (lane & 15)][(lane >> 4) * 8]; \
    _Pragma("unroll")                                                          \
    for (int n = 0; n < 4; ++n)                                                \
      bfr[n] = *(const bf16x8*)&Bs[wc + n * 16 + (lane & 15)][(lane >> 4) * 8];\
    _Pragma("unroll")                                                          \
    for (int m = 0; m < 4; ++m)                                                \
      _Pragma("unroll")                                                        \
      for (int n = 0; n < 4; ++n)                                              \
        acc[m][n] = __builtin_amdgcn_mfma_f32_16x16x32_bf16(af[m], bfr[n],     \
                                                            acc[m][n], 0, 0, 0);\
    __syncthreads();                                                           \
  }                                                                            \
  const int cr = (lane >> 4) * 4;                                              \
  const int cc = lane & 15;

// ---------- weight GEMMs: 3-way z, D row-major [N][K] layout, no bias ----------
__global__ __launch_bounds__(256) void mfma_gemm_w3(
    const unsigned short* __restrict__ A0, const unsigned short* __restrict__ A1,
    const unsigned short* __restrict__ A2,
    const unsigned short* __restrict__ B0, const unsigned short* __restrict__ B1,
    const unsigned short* __restrict__ B2,
    unsigned short* __restrict__ D0, unsigned short* __restrict__ D1,
    unsigned short* __restrict__ D2, int N, int K) {
  const int z = blockIdx.z;
  const unsigned short* A = z == 0 ? A0 : (z == 1 ? A1 : A2);
  const unsigned short* Bt = z == 0 ? B0 : (z == 1 ? B1 : B2);
  unsigned short* D = z == 0 ? D0 : (z == 1 ? D1 : D2);
  const int row0 = blockIdx.y * 128;
  const int col0 = blockIdx.x * 128;
  MFMA_PROLOG(A, Bt, K)
#pragma unroll
  for (int m = 0; m < 4; ++m) {
#pragma unroll
    for (int n = 0; n < 4; ++n) {
      const int gc = col0 + wc + n * 16 + cc;
#pragma unroll
      for (int r = 0; r < 4; ++r) {
        const int gr = row0 + wr + m * 16 + cr + r;
        D[(size_t)gr * N + gc] = f2bf(acc[m][n][r]);
      }
    }
  }
}

// ---------- the 3 big GEMMs in one dispatch, 1D XCD-swizzled grid ----------
// 1536 blocks: xcd=id&7; j=id>>3; x=j&7; rest=j>>3; y=xcd+8*(rest&7); z=rest>>3.
// All 8 x-blocks of a given (y,z) A-panel land on the same XCD -> panel L2 reuse.
// z0: tar = T_bf @ Wc1 + bc1 (mode0); z1: fc = O_bf @ Wc2 + bc2 (mode0);
// z2: tpT = (O_bf @ Wc3 + bc3) transposed-write (mode1).
__global__ __launch_bounds__(256) void mfma_gemm_big(
    const unsigned short* __restrict__ Tb, const unsigned short* __restrict__ Ob,
    const unsigned short* __restrict__ W1, const unsigned short* __restrict__ W2,
    const unsigned short* __restrict__ W3,
    const float* __restrict__ bc1, const float* __restrict__ bc2,
    const float* __restrict__ bc3,
    unsigned short* __restrict__ Dtar, unsigned short* __restrict__ Dfc,
    unsigned short* __restrict__ DtpT) {
  const int id = blockIdx.x;
  const int xcd = id & 7;
  const int j = id >> 3;
  const int x = j & 7;
  const int rest = j >> 3;               // 0..23
  const int y = xcd + ((rest & 7) << 3); // 0..63
  const int z = rest >> 3;               // 0..2
  const unsigned short* A = z == 0 ? Tb : Ob;
  const unsigned short* Bt = z == 0 ? W1 : (z == 1 ? W2 : W3);
  const float* bias = z == 0 ? bc1 : (z == 1 ? bc2 : bc3);
  const int row0 = y * 128;
  const int col0 = x * 128;
  MFMA_PROLOG(A, Bt, Hn)
  if (z != 2) {
    unsigned short* D = z == 0 ? Dtar : Dfc;
#pragma unroll
    for (int m = 0; m < 4; ++m) {
#pragma unroll
      for (int n = 0; n < 4; ++n) {
        const int gc = col0 + wc + n * 16 + cc;
        const float bv = bias[gc];
#pragma unroll
        for (int r = 0; r < 4; ++r) {
          const int gr = row0 + wr + m * 16 + cr + r;
          D[(size_t)gr * Hn + gc] = f2bf(acc[m][n][r] + bv);
        }
      }
    }
  } else {
    // transposed write: gr = b*512 + o; store DtpT[(b*Hn+gc)*Ln + o], 4 o's packed
#pragma unroll
    for (int m = 0; m < 4; ++m) {
      const int gr0 = row0 + wr + m * 16 + cr;   // o-contiguous base (mult of 4)
      const int b = gr0 >> 9;
      const int o = gr0 & 511;
#pragma unroll
      for (int n = 0; n < 4; ++n) {
        const int gc = col0 + wc + n * 16 + cc;
        const float bv = bias[gc];
        ushort4 w;
        w.x = f2bf(acc[m][n][0] + bv);
        w.y = f2bf(acc[m][n][1] + bv);
        w.z = f2bf(acc[m][n][2] + bv);
        w.w = f2bf(acc[m][n][3] + bv);
        *(ushort4*)(DtpT + ((size_t)b * Hn + gc) * Ln + o) = w;
      }
    }
  }
}

// ---------- Q[b][t][o] = exp(20 * <tar_t, fc_o> * rt[b,t] * rf[b,o]) ----------
__global__ __launch_bounds__(256) void mfma_cos_exp(
    const unsigned short* __restrict__ TarBf, const unsigned short* __restrict__ FcBf,
    const float* __restrict__ rt, const float* __restrict__ rf,
    float* __restrict__ Q) {
  const int b = blockIdx.z;
  const unsigned short* Ab = TarBf + (size_t)b * Ln * Hn;
  const unsigned short* Bb = FcBf + (size_t)b * Ln * Hn;
  float* Qb = Q + (size_t)b * Ln * Ln;
  const int row0 = blockIdx.y * 128;  // t
  const int col0 = blockIdx.x * 128;  // o
  MFMA_PROLOG(Ab, Bb, Hn)
#pragma unroll
  for (int m = 0; m < 4; ++m) {
#pragma unroll
    for (int n = 0; n < 4; ++n) {
      const int o = col0 + wc + n * 16 + cc;
      const float rfo = rf[b * Ln + o] * 20.0f;
#pragma unroll
      for (int r = 0; r < 4; ++r) {
        const int t = row0 + wr + m * 16 + cr + r;
        const float c = acc[m][n][r] * rt[b * Ln + t] * rfo;
        Qb[(size_t)t * Ln + o] = __expf(c);
      }
    }
  }
}

// ---------- Out[b][t][h] = plan[b][t][:] @ tpT[b][h][:]^T + tar[b][t][h] ----------
__global__ __launch_bounds__(256) void mfma_out(
    const unsigned short* __restrict__ Plan, const unsigned short* __restrict__ TpT,
    const unsigned short* __restrict__ TarBf, float* __restrict__ Out) {
  const int b = blockIdx.z;
  const unsigned short* Ab = Plan + (size_t)b * Ln * Ln;
  const unsigned short* Bb = TpT + (size_t)b * Hn * Ln;
  const int row0 = blockIdx.y * 128;  // t
  const int col0 = blockIdx.x * 128;  // h
  MFMA_PROLOG(Ab, Bb, Ln)
#pragma unroll
  for (int m = 0; m < 4; ++m) {
#pragma unroll
    for (int n = 0; n < 4; ++n) {
      const int h = col0 + wc + n * 16 + cc;
#pragma unroll
      for (int r = 0; r < 4; ++r) {
        const int t = row0 + wr + m * 16 + cr + r;
        const size_t off = ((size_t)b * Ln + t) * Hn + h;
        Out[off] = acc[m][n][r] + bf2f(TarBf[off]);
      }
    }
  }
}

// ---------- r[row] = 1/max(||X_row||, eps), z-batched ----------
__global__ __launch_bounds__(256) void rownorm_z(
    const unsigned short* __restrict__ X0, const unsigned short* __restrict__ X1,
    float* __restrict__ r0, float* __restrict__ r1, float eps) {
  const unsigned short* X = blockIdx.y ? X1 : X0;
  float* r = blockIdx.y ? r1 : r0;
  const unsigned short* row = X + (size_t)blockIdx.x * Hn;
  const int i = threadIdx.x * 4;
  ushort4 v = *(const ushort4*)(row + i);
  float a0 = bf2f(v.x), a1 = bf2f(v.y), a2 = bf2f(v.z), a3 = bf2f(v.w);
  float s = block_reduce_sum(a0 * a0 + a1 * a1 + a2 * a2 + a3 * a3);
  if (threadIdx.x == 0) r[blockIdx.x] = 1.0f / fmaxf(sqrtf(s), eps);
}

// ---------- fused Sinkhorn (5 iters) + plan prep: one block per batch ----------
// u = 1/(Q v), v = 1/(Q^T u); plan = l2norm_row(Q . v) -> bf16 (u cancels).
__global__ __launch_bounds__(1024) void sinkhorn_fused(
    const float* __restrict__ Q, unsigned short* __restrict__ P) {
  const int b = blockIdx.x;
  const float* Qb = Q + (size_t)b * Ln * Ln;
  __shared__ __align__(16) float vsh[Ln];
  __shared__ __align__(16) float ush[Ln];
  __shared__ float part[1024];
  const int tid = threadIdx.x;
  const int wv = tid >> 6;      // 0..15
  const int lane = tid & 63;
  const int o = tid & 511;
  const int half = tid >> 9;    // 0 or 1
  if (tid < Ln) vsh[tid] = 1.0f;
  __syncthreads();
  for (int it = 0; it < 5; ++it) {
    // u-step: one wave per row, 32 rows per wave
    for (int r = wv; r < Ln; r += 16) {
      const float* q = Qb + (size_t)r * Ln;
      const float4 a = *(const float4*)(q + lane * 8);
      const float4 c = *(const float4*)(q + lane * 8 + 4);
      const float4 va = *(const float4*)(vsh + lane * 8);
      const float4 vc = *(const float4*)(vsh + lane * 8 + 4);
      float s = a.x * va.x + a.y * va.y + a.z * va.z + a.w * va.w +
                c.x * vc.x + c.y * vc.y + c.z * vc.z + c.w * vc.w;
#pragma unroll
      for (int off = 32; off > 0; off >>= 1) s += __shfl_down(s, off, 64);
      if (lane == 0) ush[r] = 1.0f / s;
    }
    __syncthreads();
    // v-step: thread (half,o) sums 256 t's; pair-combine via LDS
    float s = 0.f;
    const int t0 = half * 256;
#pragma unroll 4
    for (int t = t0; t < t0 + 256; ++t) s += Qb[(size_t)t * Ln + o] * ush[t];
    part[tid] = s;
    __syncthreads();
    if (tid < Ln) vsh[tid] = 1.0f / (part[tid] + part[tid + 512]);
    __syncthreads();
  }
  // plan: one wave per row; p = q*v, row-l2-normalize, write bf16
  for (int r = wv; r < Ln; r += 16) {
    const float* q = Qb + (size_t)r * Ln;
    const float4 a = *(const float4*)(q + lane * 8);
    const float4 c = *(const float4*)(q + lane * 8 + 4);
    const float4 va = *(const float4*)(vsh + lane * 8);
    const float4 vc = *(const float4*)(vsh + lane * 8 + 4);
    float p[8];
    p[0] = a.x * va.x; p[1] = a.y * va.y; p[2] = a.z * va.z; p[3] = a.w * va.w;
    p[4] = c.x * vc.x; p[5] = c.y * vc.y; p[6] = c.z * vc.z; p[7] = c.w * vc.w;
    float s = 0.f;
#pragma unroll
    for (int k = 0; k < 8; ++k) s += p[k] * p[k];
#pragma unroll
    for (int off = 32; off > 0; off >>= 1) s += __shfl_down(s, off, 64);
    s = __shfl(s, 0, 64);
    const float rn = 1.0f / fmaxf(sqrtf(s), 1e-12f);
    u16x8 w;
#pragma unroll
    for (int k = 0; k < 8; ++k) w[k] = f2bf(p[k] * rn);
    *(u16x8*)(P + ((size_t)b * Ln + r) * Ln + lane * 8) = w;
  }
}

// ---------- LayerNorm over last dim, in-place ----------
__global__ __launch_bounds__(256) void ln_kernel(
    float* __restrict__ Out, const float* __restrict__ g, const float* __restrict__ b) {
  float* row = Out + (size_t)blockIdx.x * Hn;
  const int tid = threadIdx.x;
  float4 v = reinterpret_cast<float4*>(row)[tid];
  float s = v.x + v.y + v.z + v.w;
  float ss = v.x * v.x + v.y * v.y + v.z * v.z + v.w * v.w;
  const float tot = block_reduce_sum(s);
  const float tot2 = block_reduce_sum(ss);
  const float mu = tot * (1.0f / Hn);
  const float var = tot2 * (1.0f / Hn) - mu * mu;
  const float rs = rsqrtf(var + 1e-5f);
  const float4 gg = reinterpret_cast<const float4*>(g)[tid];
  const float4 bb = reinterpret_cast<const float4*>(b)[tid];
  v.x = (v.x - mu) * rs * gg.x + bb.x;
  v.y = (v.y - mu) * rs * gg.y + bb.y;
  v.z = (v.z - mu) * rs * gg.z + bb.z;
  v.w = (v.w - mu) * rs * gg.w + bb.w;
  reinterpret_cast<float4*>(row)[tid] = v;
}

extern "C" void kernel_launch(void* const* d_in, const int* in_sizes, int n_in,
                              void* d_out, int out_size, void* d_ws, size_t ws_size,
                              hipStream_t stream) {
  const float* origin = (const float*)d_in[0];
  const float* target = (const float*)d_in[1];
  const float* W_ori = (const float*)d_in[2];
  const float* b_ori = (const float*)d_in[3];
  const float* W_tar = (const float*)d_in[4];
  const float* b_tar = (const float*)d_in[5];
  const float* W_ft = (const float*)d_in[6];
  const float* b_ft = (const float*)d_in[7];
  const float* W_fo = (const float*)d_in[8];
  const float* b_fo = (const float*)d_in[9];
  const float* W_fot = (const float*)d_in[10];
  const float* b_fot = (const float*)d_in[11];
  const float* ln_g = (const float*)d_in[12];
  const float* ln_b = (const float*)d_in[13];
  float* out = (float*)d_out;

  // ---- workspace layout, 96 MiB + small (lifetime-overlapped) ----
  // [0,16M):   O_bf (-> bigGEMM)  -> Qw f32 (cos -> sinkhorn)
  // [16,32M):  T_bf (-> bigGEMM)  -> plan_bf (8M, sinkhorn -> mfma_out)
  // [32,48M):  tar_bf (bigGEMM -> end)
  // [48,64M):  fc_bf  (bigGEMM -> cos)
  // [64,80M):  tpT    (bigGEMM mode1 -> mfma_out)
  // [80,96M):  Wc1T@80, Wc2T@82, Wc3T@84, Wtar_bf@86, Wori_bf@88,
  //            WftT@90, WfoT@92, WfotT@94  (all bf16 2M each)
  // [96M..):   bc1,bc2,bc3 (4KB each), rt, rf (32KB each)
  char* ws = (char*)d_ws;
  const size_t MB = 1048576;
  unsigned short* O_bf = (unsigned short*)(ws + 0);
  float* Qw = (float*)(ws + 0);
  unsigned short* T_bf = (unsigned short*)(ws + 16 * MB);
  unsigned short* plan_bf = (unsigned short*)(ws + 16 * MB);
  unsigned short* tar_bf = (unsigned short*)(ws + 32 * MB);
  unsigned short* fc_bf = (unsigned short*)(ws + 48 * MB);
  unsigned short* tpT = (unsigned short*)(ws + 64 * MB);
  unsigned short* Wc1T = (unsigned short*)(ws + 80 * MB);
  unsigned short* Wc2T = (unsigned short*)(ws + 82 * MB);
  unsigned short* Wc3T = (unsigned short*)(ws + 84 * MB);
  unsigned short* Wtar_bf = (unsigned short*)(ws + 86 * MB);
  unsigned short* Wori_bf = (unsigned short*)(ws + 88 * MB);
  unsigned short* WftT = (unsigned short*)(ws + 90 * MB);
  unsigned short* WfoT = (unsigned short*)(ws + 92 * MB);
  unsigned short* WfotT = (unsigned short*)(ws + 94 * MB);
  float* bc1 = (float*)(ws + 96 * MB);
  float* bc2 = bc1 + 1024;
  float* bc3 = bc2 + 1024;
  float* rt = bc3 + 1024;
  float* rf = rt + RowsT;

  const dim3 blk(256);

  // 1) quantize activations: origin->O_bf, target->T_bf
  conv_z<<<dim3(RowsT * Hn / 2048, 1, 2), blk, 0, stream>>>(origin, target, O_bf, T_bf);
  // 2) quantize W_tar, W_ori
  conv_z<<<dim3(Hn * Hn / 2048, 1, 2), blk, 0, stream>>>(W_tar, W_ori, Wtar_bf, Wori_bf);
  // 3) transpose W_ft, W_fo, W_fot -> [N][K] bf16
  transpose_w3<<<dim3(32, 32, 3), blk, 0, stream>>>(W_ft, W_fo, W_fot,
                                                    WftT, WfoT, WfotT, Hn, Hn);
  // 4) combined biases
  bias_combine<<<dim3(4, 3), blk, 0, stream>>>(b_tar, W_ft, b_ft, b_ori, W_fo, b_fo,
                                               b_ori, W_fot, b_fot, bc1, bc2, bc3);
  // 5) combined weights: Wc1^T=(W_tar@W_ft)^T, Wc2^T=(W_ori@W_fo)^T, Wc3^T=(W_ori@W_fot)^T
  mfma_gemm_w3<<<dim3(8, 8, 3), blk, 0, stream>>>(WftT, WfoT, WfotT,
                                                  Wtar_bf, Wori_bf, Wori_bf,
                                                  Wc1T, Wc2T, Wc3T, Hn, Hn);
  // 6) the three big GEMMs, one dispatch, XCD-swizzled
  mfma_gemm_big<<<dim3(1536), blk, 0, stream>>>(T_bf, O_bf, Wc1T, Wc2T, Wc3T,
                                                bc1, bc2, bc3, tar_bf, fc_bf, tpT);
  // 7) cosine norms
  rownorm_z<<<dim3(RowsT, 2), blk, 0, stream>>>(tar_bf, fc_bf, rt, rf, 1e-8f);
  // 8) Q = exp(cos/0.05)  (into dead O region)
  mfma_cos_exp<<<dim3(4, 4, Bn), blk, 0, stream>>>(tar_bf, fc_bf, rt, rf, Qw);
  // 9) fused Sinkhorn + plan prep (one block per batch; plan over dead T region)
  sinkhorn_fused<<<dim3(Bn), dim3(1024), 0, stream>>>(Qw, plan_bf);
  // 10) out = plan @ tp + tar
  mfma_out<<<dim3(Hn / 128, Ln / 128, Bn), blk, 0, stream>>>(plan_bf, tpT, tar_bf, out);
  // 11) LayerNorm in-place
  ln_kernel<<<dim3(RowsT), blk, 0, stream>>>(out, ln_g, ln_b);
}

// Round 7
// 426.745 us; speedup vs baseline: 2.3306x; 1.1239x over previous
//
#include <hip/hip_runtime.h>
#include <hip/hip_bf16.h>
#include <math.h>

// Problem constants
constexpr int Bn = 16;
constexpr int Ln = 512;
constexpr int Hn = 1024;
constexpr int RowsT = Bn * Ln;  // 8192

typedef __attribute__((ext_vector_type(8))) short bf16x8;
typedef __attribute__((ext_vector_type(4))) float f32x4;
typedef __attribute__((ext_vector_type(8))) unsigned short u16x8;

__device__ __forceinline__ unsigned short f2bf(float f) {  // RNE f32->bf16
  unsigned u = __float_as_uint(f);
  u += 0x7FFFu + ((u >> 16) & 1u);
  return (unsigned short)(u >> 16);
}
__device__ __forceinline__ float bf2f(unsigned short u) {
  return __uint_as_float(((unsigned)u) << 16);
}

__device__ __forceinline__ void gload_lds16(const void* g, void* l) {
  __builtin_amdgcn_global_load_lds(
      (const __attribute__((address_space(1))) void*)g,
      (__attribute__((address_space(3))) void*)l, 16, 0, 0);
}

// ---------------- block-wide reduction (256 threads) ----------------
__device__ __forceinline__ float block_reduce_sum(float v) {
  __shared__ float sbuf[8];
  const int lane = threadIdx.x & 63;
  const int wid = threadIdx.x >> 6;
#pragma unroll
  for (int off = 32; off > 0; off >>= 1) v += __shfl_down(v, off, 64);
  __syncthreads();
  if (lane == 0) sbuf[wid] = v;
  __syncthreads();
  if (threadIdx.x == 0) {
    float t = 0.f;
    const int nw = (blockDim.x + 63) >> 6;
    for (int i = 0; i < nw; ++i) t += sbuf[i];
    sbuf[0] = t;
  }
  __syncthreads();
  return sbuf[0];
}

// ---------- f32 -> bf16, z-batched (8 elems/thread) ----------
__global__ __launch_bounds__(256) void conv_z(
    const float* __restrict__ s0, const float* __restrict__ s1,
    unsigned short* __restrict__ d0, unsigned short* __restrict__ d1) {
  const float* in = blockIdx.z ? s1 : s0;
  unsigned short* out = blockIdx.z ? d1 : d0;
  const size_t i = ((size_t)blockIdx.x * blockDim.x + threadIdx.x) * 8;
  const float4 a = *(const float4*)(in + i);
  const float4 b = *(const float4*)(in + i + 4);
  u16x8 r;
  r[0] = f2bf(a.x); r[1] = f2bf(a.y); r[2] = f2bf(a.z); r[3] = f2bf(a.w);
  r[4] = f2bf(b.x); r[5] = f2bf(b.y); r[6] = f2bf(b.z); r[7] = f2bf(b.w);
  *(u16x8*)(out + i) = r;
}

// ---------- W[K][N] f32 -> Wt[N][K] bf16, 3-way z ----------
__global__ __launch_bounds__(256) void transpose_w3(
    const float* __restrict__ s0, const float* __restrict__ s1, const float* __restrict__ s2,
    unsigned short* __restrict__ d0, unsigned short* __restrict__ d1,
    unsigned short* __restrict__ d2, int K, int N) {
  const int z = blockIdx.z;
  const float* W = z == 0 ? s0 : (z == 1 ? s1 : s2);
  unsigned short* Wt = z == 0 ? d0 : (z == 1 ? d1 : d2);
  __shared__ float t[32][33];
  const int n0 = blockIdx.x * 32;
  const int k0 = blockIdx.y * 32;
  const int tx = threadIdx.x & 31;
  const int ty = threadIdx.x >> 5;
#pragma unroll
  for (int i = 0; i < 32; i += 8)
    t[ty + i][tx] = W[(size_t)(k0 + ty + i) * N + n0 + tx];
  __syncthreads();
#pragma unroll
  for (int i = 0; i < 32; i += 8)
    Wt[(size_t)(n0 + ty + i) * K + k0 + tx] = f2bf(t[tx][ty + i]);
}

// ---------- bc[n] = sum_j b1[j]*W[j][n] + b2[n], z-batched (3) ----------
__global__ __launch_bounds__(256) void bias_combine(
    const float* __restrict__ b1a, const float* __restrict__ Wa, const float* __restrict__ b2a,
    const float* __restrict__ b1b, const float* __restrict__ Wb, const float* __restrict__ b2b,
    const float* __restrict__ b1c, const float* __restrict__ Wc, const float* __restrict__ b2c,
    float* __restrict__ o0, float* __restrict__ o1, float* __restrict__ o2) {
  const int z = blockIdx.y;
  const float* b1 = z == 0 ? b1a : (z == 1 ? b1b : b1c);
  const float* W  = z == 0 ? Wa  : (z == 1 ? Wb  : Wc);
  const float* b2 = z == 0 ? b2a : (z == 1 ? b2b : b2c);
  float* out      = z == 0 ? o0  : (z == 1 ? o1  : o2);
  const int n = blockIdx.x * 256 + threadIdx.x;
  float s = b2[n];
  for (int j = 0; j < Hn; ++j) s += b1[j] * W[(size_t)j * Hn + n];
  out[n] = s;
}

// ================= MFMA GEMM core (m97 structure: 128x128, BK=32) =================
#define MFMA_PROLOG(Aptr, Bptr, Kdim)                                          \
  constexpr int BK = 32;                                                       \
  __shared__ unsigned short As[128][BK];                                       \
  __shared__ unsigned short Bs[128][BK];                                       \
  const int tid = threadIdx.x;                                                 \
  const int wid = tid >> 6;                                                    \
  const int lane = tid & 63;                                                   \
  const int wr = (wid >> 1) * 64;                                              \
  const int wc = (wid & 1) * 64;                                               \
  const int sr = lane >> 2;                                                    \
  const int sk = (lane & 3) * 8;                                               \
  const size_t arow = (size_t)(row0 + wid * 32 + sr) * Kdim + sk;              \
  const size_t brow = (size_t)(col0 + wid * 32 + sr) * Kdim + sk;              \
  f32x4 acc[4][4] = {};                                                        \
  for (int k0 = 0; k0 < Kdim; k0 += BK) {                                      \
    gload_lds16(Aptr + arow + k0,                      &As[wid * 32][0]);      \
    gload_lds16(Aptr + arow + (size_t)16 * Kdim + k0,  &As[wid * 32 + 16][0]); \
    gload_lds16(Bptr + brow + k0,                      &Bs[wid * 32][0]);      \
    gload_lds16(Bptr + brow + (size_t)16 * Kdim + k0,  &Bs[wid * 32 + 16][0]); \
    __syncthreads();                                                           \
    bf16x8 af[4], bfr[4];                                                      \
    _Pragma("unroll")                                                          \
    for (int m = 0; m < 4; ++m)                                                \
      af[m] = *(const bf16x8*)&As[wr + m * 16 + (lane & 15)][(lane >> 4) * 8]; \
    _Pragma("unroll")                                                          \
    for (int n = 0; n < 4; ++n)                                                \
      bfr[n] = *(const bf16x8*)&Bs[wc + n * 16 + (lane & 15)][(lane >> 4) * 8];\
    _Pragma("unroll")                                                          \
    for (int m = 0; m < 4; ++m)                                                \
      _Pragma("unroll")                                                        \
      for (int n = 0; n < 4; ++n)                                              \
        acc[m][n] = __builtin_amdgcn_mfma_f32_16x16x32_bf16(af[m], bfr[n],     \
                                                            acc[m][n], 0, 0, 0);\
    __syncthreads();                                                           \
  }                                                                            \
  const int cr = (lane >> 4) * 4;                                              \
  const int cc = lane & 15;

// ---------- weight GEMMs: 3-way z, D row-major [N][K] layout, no bias ----------
__global__ __launch_bounds__(256) void mfma_gemm_w3(
    const unsigned short* __restrict__ A0, const unsigned short* __restrict__ A1,
    const unsigned short* __restrict__ A2,
    const unsigned short* __restrict__ B0, const unsigned short* __restrict__ B1,
    const unsigned short* __restrict__ B2,
    unsigned short* __restrict__ D0, unsigned short* __restrict__ D1,
    unsigned short* __restrict__ D2, int N, int K) {
  const int z = blockIdx.z;
  const unsigned short* A = z == 0 ? A0 : (z == 1 ? A1 : A2);
  const unsigned short* Bt = z == 0 ? B0 : (z == 1 ? B1 : B2);
  unsigned short* D = z == 0 ? D0 : (z == 1 ? D1 : D2);
  const int row0 = blockIdx.y * 128;
  const int col0 = blockIdx.x * 128;
  MFMA_PROLOG(A, Bt, K)
#pragma unroll
  for (int m = 0; m < 4; ++m) {
#pragma unroll
    for (int n = 0; n < 4; ++n) {
      const int gc = col0 + wc + n * 16 + cc;
#pragma unroll
      for (int r = 0; r < 4; ++r) {
        const int gr = row0 + wr + m * 16 + cr + r;
        D[(size_t)gr * N + gc] = f2bf(acc[m][n][r]);
      }
    }
  }
}

// ---------- the 3 big GEMMs in one dispatch, 1D XCD-swizzled grid ----------
__global__ __launch_bounds__(256) void mfma_gemm_big(
    const unsigned short* __restrict__ Tb, const unsigned short* __restrict__ Ob,
    const unsigned short* __restrict__ W1, const unsigned short* __restrict__ W2,
    const unsigned short* __restrict__ W3,
    const float* __restrict__ bc1, const float* __restrict__ bc2,
    const float* __restrict__ bc3,
    unsigned short* __restrict__ Dtar, unsigned short* __restrict__ Dfc,
    unsigned short* __restrict__ DtpT) {
  const int id = blockIdx.x;
  const int xcd = id & 7;
  const int j = id >> 3;
  const int x = j & 7;
  const int rest = j >> 3;               // 0..23
  const int y = xcd + ((rest & 7) << 3); // 0..63
  const int z = rest >> 3;               // 0..2
  const unsigned short* A = z == 0 ? Tb : Ob;
  const unsigned short* Bt = z == 0 ? W1 : (z == 1 ? W2 : W3);
  const float* bias = z == 0 ? bc1 : (z == 1 ? bc2 : bc3);
  const int row0 = y * 128;
  const int col0 = x * 128;
  MFMA_PROLOG(A, Bt, Hn)
  if (z != 2) {
    unsigned short* D = z == 0 ? Dtar : Dfc;
#pragma unroll
    for (int m = 0; m < 4; ++m) {
#pragma unroll
      for (int n = 0; n < 4; ++n) {
        const int gc = col0 + wc + n * 16 + cc;
        const float bv = bias[gc];
#pragma unroll
        for (int r = 0; r < 4; ++r) {
          const int gr = row0 + wr + m * 16 + cr + r;
          D[(size_t)gr * Hn + gc] = f2bf(acc[m][n][r] + bv);
        }
      }
    }
  } else {
    // transposed write: gr = b*512 + o; store DtpT[(b*Hn+gc)*Ln + o], 4 o's packed
#pragma unroll
    for (int m = 0; m < 4; ++m) {
      const int gr0 = row0 + wr + m * 16 + cr;   // o-contiguous base (mult of 4)
      const int b = gr0 >> 9;
      const int o = gr0 & 511;
#pragma unroll
      for (int n = 0; n < 4; ++n) {
        const int gc = col0 + wc + n * 16 + cc;
        const float bv = bias[gc];
        ushort4 w;
        w.x = f2bf(acc[m][n][0] + bv);
        w.y = f2bf(acc[m][n][1] + bv);
        w.z = f2bf(acc[m][n][2] + bv);
        w.w = f2bf(acc[m][n][3] + bv);
        *(ushort4*)(DtpT + ((size_t)b * Hn + gc) * Ln + o) = w;
      }
    }
  }
}

// ---------- Q[b][t][o] = exp(20*<tar_t,fc_o>*rt*rf), 1D XCD-swizzled (256 blk) ----------
__global__ __launch_bounds__(256) void mfma_cos_exp(
    const unsigned short* __restrict__ TarBf, const unsigned short* __restrict__ FcBf,
    const float* __restrict__ rt, const float* __restrict__ rf,
    float* __restrict__ Q) {
  const int id = blockIdx.x;
  const int xcd = id & 7;
  const int r2 = id >> 3;                 // 0..31
  const int x = r2 & 3;                   // o-tile
  const int yb = xcd + ((r2 >> 2) << 3);  // 0..63
  const int y = yb & 3;                   // t-tile
  const int b = yb >> 2;                  // batch
  const unsigned short* Ab = TarBf + (size_t)b * Ln * Hn;
  const unsigned short* Bb = FcBf + (size_t)b * Ln * Hn;
  float* Qb = Q + (size_t)b * Ln * Ln;
  const int row0 = y * 128;  // t
  const int col0 = x * 128;  // o
  MFMA_PROLOG(Ab, Bb, Hn)
#pragma unroll
  for (int m = 0; m < 4; ++m) {
#pragma unroll
    for (int n = 0; n < 4; ++n) {
      const int o = col0 + wc + n * 16 + cc;
      const float rfo = rf[b * Ln + o] * 20.0f;
#pragma unroll
      for (int r = 0; r < 4; ++r) {
        const int t = row0 + wr + m * 16 + cr + r;
        const float c = acc[m][n][r] * rt[b * Ln + t] * rfo;
        Qb[(size_t)t * Ln + o] = __expf(c);
      }
    }
  }
}

// ---------- Out = plan @ tpT^T + tar, 1D XCD-swizzled (512 blocks) ----------
__global__ __launch_bounds__(256) void mfma_out(
    const unsigned short* __restrict__ Plan, const unsigned short* __restrict__ TpT,
    const unsigned short* __restrict__ TarBf, float* __restrict__ Out) {
  const int id = blockIdx.x;
  const int xcd = id & 7;
  const int r2 = id >> 3;                 // 0..63
  const int x = r2 & 7;                   // h-tile
  const int yb = xcd + ((r2 >> 3) << 3);  // 0..63
  const int y = yb & 3;                   // t-tile
  const int b = yb >> 2;                  // batch
  const unsigned short* Ab = Plan + (size_t)b * Ln * Ln;
  const unsigned short* Bb = TpT + (size_t)b * Hn * Ln;
  const int row0 = y * 128;  // t
  const int col0 = x * 128;  // h
  MFMA_PROLOG(Ab, Bb, Ln)
#pragma unroll
  for (int m = 0; m < 4; ++m) {
#pragma unroll
    for (int n = 0; n < 4; ++n) {
      const int h = col0 + wc + n * 16 + cc;
#pragma unroll
      for (int r = 0; r < 4; ++r) {
        const int t = row0 + wr + m * 16 + cr + r;
        const size_t off = ((size_t)b * Ln + t) * Hn + h;
        Out[off] = acc[m][n][r] + bf2f(TarBf[off]);
      }
    }
  }
}

// ---------- r[row] = 1/max(||X_row||, eps), z-batched ----------
__global__ __launch_bounds__(256) void rownorm_z(
    const unsigned short* __restrict__ X0, const unsigned short* __restrict__ X1,
    float* __restrict__ r0, float* __restrict__ r1, float eps) {
  const unsigned short* X = blockIdx.y ? X1 : X0;
  float* r = blockIdx.y ? r1 : r0;
  const unsigned short* row = X + (size_t)blockIdx.x * Hn;
  const int i = threadIdx.x * 4;
  ushort4 v = *(const ushort4*)(row + i);
  float a0 = bf2f(v.x), a1 = bf2f(v.y), a2 = bf2f(v.z), a3 = bf2f(v.w);
  float s = block_reduce_sum(a0 * a0 + a1 * a1 + a2 * a2 + a3 * a3);
  if (threadIdx.x == 0) r[blockIdx.x] = 1.0f / fmaxf(sqrtf(s), eps);
}

// ---------- u[row] = 1 / dot(Q[row,:], v[b,:])  (one wave per row, 2048 blocks) ----------
template<bool FIRST>
__global__ __launch_bounds__(256) void u_step(
    const float* __restrict__ Q, const float* __restrict__ v, float* __restrict__ u) {
  const int row = blockIdx.x * 4 + (threadIdx.x >> 6);
  const int b = row >> 9;
  const int lane = threadIdx.x & 63;
  const float* q = Q + (size_t)row * Ln;
  const float4 a = *(const float4*)(q + lane * 8);
  const float4 c = *(const float4*)(q + lane * 8 + 4);
  float s;
  if (FIRST) {
    s = a.x + a.y + a.z + a.w + c.x + c.y + c.z + c.w;
  } else {
    const float* vb = v + b * Ln;
    const float4 va = *(const float4*)(vb + lane * 8);
    const float4 vc = *(const float4*)(vb + lane * 8 + 4);
    s = a.x * va.x + a.y * va.y + a.z * va.z + a.w * va.w +
        c.x * vc.x + c.y * vc.y + c.z * vc.z + c.w * vc.w;
  }
#pragma unroll
  for (int off = 32; off > 0; off >>= 1) s += __shfl_down(s, off, 64);
  if (lane == 0) u[row] = 1.0f / s;
}

// ---------- v[b,o] = 1 / sum_t Q[b][t][o]*u[b,t]   ((8,16) grid) ----------
__global__ __launch_bounds__(256) void v_step(
    const float* __restrict__ Q, const float* __restrict__ u, float* __restrict__ v) {
  const int b = blockIdx.y;
  const float* Qb = Q + (size_t)b * Ln * Ln;
  __shared__ float us[Ln];
  __shared__ float part[4][64];
  const int tid = threadIdx.x;
  us[tid] = u[b * Ln + tid];
  us[tid + 256] = u[b * Ln + tid + 256];
  __syncthreads();
  const int c = tid & 63;
  const int chunk = tid >> 6;
  const int o = blockIdx.x * 64 + c;
  float s = 0.f;
#pragma unroll 4
  for (int t = chunk * 128; t < chunk * 128 + 128; ++t)
    s += Qb[(size_t)t * Ln + o] * us[t];
  part[chunk][c] = s;
  __syncthreads();
  if (chunk == 0)
    v[b * Ln + o] = 1.0f / (part[0][c] + part[1][c] + part[2][c] + part[3][c]);
}

// ---------- plan_bf = bf16( Q.v / max(||row(Q.v)||, 1e-12) )  (8192 blocks) ----------
__global__ __launch_bounds__(256) void plan_prep(
    const float* __restrict__ Q, const float* __restrict__ v,
    unsigned short* __restrict__ P) {
  const int row = blockIdx.x;
  const int b = row >> 9;
  const float* q = Q + (size_t)row * Ln;
  const float* vb = v + b * Ln;
  const int i = threadIdx.x * 2;
  const float2 qq = *(const float2*)(q + i);
  const float2 vv = *(const float2*)(vb + i);
  const float p0 = qq.x * vv.x, p1 = qq.y * vv.y;
  const float s = block_reduce_sum(p0 * p0 + p1 * p1);
  const float rn = 1.0f / fmaxf(sqrtf(s), 1e-12f);
  ushort2 w;
  w.x = f2bf(p0 * rn);
  w.y = f2bf(p1 * rn);
  *(ushort2*)(P + (size_t)row * Ln + i) = w;
}

// ---------- LayerNorm over last dim, in-place ----------
__global__ __launch_bounds__(256) void ln_kernel(
    float* __restrict__ Out, const float* __restrict__ g, const float* __restrict__ b) {
  float* row = Out + (size_t)blockIdx.x * Hn;
  const int tid = threadIdx.x;
  float4 v = reinterpret_cast<float4*>(row)[tid];
  float s = v.x + v.y + v.z + v.w;
  float ss = v.x * v.x + v.y * v.y + v.z * v.z + v.w * v.w;
  const float tot = block_reduce_sum(s);
  const float tot2 = block_reduce_sum(ss);
  const float mu = tot * (1.0f / Hn);
  const float var = tot2 * (1.0f / Hn) - mu * mu;
  const float rs = rsqrtf(var + 1e-5f);
  const float4 gg = reinterpret_cast<const float4*>(g)[tid];
  const float4 bb = reinterpret_cast<const float4*>(b)[tid];
  v.x = (v.x - mu) * rs * gg.x + bb.x;
  v.y = (v.y - mu) * rs * gg.y + bb.y;
  v.z = (v.z - mu) * rs * gg.z + bb.z;
  v.w = (v.w - mu) * rs * gg.w + bb.w;
  reinterpret_cast<float4*>(row)[tid] = v;
}

extern "C" void kernel_launch(void* const* d_in, const int* in_sizes, int n_in,
                              void* d_out, int out_size, void* d_ws, size_t ws_size,
                              hipStream_t stream) {
  const float* origin = (const float*)d_in[0];
  const float* target = (const float*)d_in[1];
  const float* W_ori = (const float*)d_in[2];
  const float* b_ori = (const float*)d_in[3];
  const float* W_tar = (const float*)d_in[4];
  const float* b_tar = (const float*)d_in[5];
  const float* W_ft = (const float*)d_in[6];
  const float* b_ft = (const float*)d_in[7];
  const float* W_fo = (const float*)d_in[8];
  const float* b_fo = (const float*)d_in[9];
  const float* W_fot = (const float*)d_in[10];
  const float* b_fot = (const float*)d_in[11];
  const float* ln_g = (const float*)d_in[12];
  const float* ln_b = (const float*)d_in[13];
  float* out = (float*)d_out;

  // ---- workspace layout, 96 MiB + small (lifetime-overlapped) ----
  // [0,16M):   O_bf (-> bigGEMM)  -> Qw f32 (cos -> plan_prep)
  // [16,32M):  T_bf (-> bigGEMM)  -> plan_bf (8M, plan_prep -> mfma_out)
  // [32,48M):  tar_bf (bigGEMM -> end)
  // [48,64M):  fc_bf  (bigGEMM -> cos)
  // [64,80M):  tpT    (bigGEMM mode1 -> mfma_out)
  // [80,96M):  Wc1T@80, Wc2T@82, Wc3T@84, Wtar_bf@86, Wori_bf@88,
  //            WftT@90, WfoT@92, WfotT@94  (all bf16 2M each)
  // [96M..):   bc1,bc2,bc3 (4KB each), rt, rf, uu, vv (32KB each)
  char* ws = (char*)d_ws;
  const size_t MB = 1048576;
  unsigned short* O_bf = (unsigned short*)(ws + 0);
  float* Qw = (float*)(ws + 0);
  unsigned short* T_bf = (unsigned short*)(ws + 16 * MB);
  unsigned short* plan_bf = (unsigned short*)(ws + 16 * MB);
  unsigned short* tar_bf = (unsigned short*)(ws + 32 * MB);
  unsigned short* fc_bf = (unsigned short*)(ws + 48 * MB);
  unsigned short* tpT = (unsigned short*)(ws + 64 * MB);
  unsigned short* Wc1T = (unsigned short*)(ws + 80 * MB);
  unsigned short* Wc2T = (unsigned short*)(ws + 82 * MB);
  unsigned short* Wc3T = (unsigned short*)(ws + 84 * MB);
  unsigned short* Wtar_bf = (unsigned short*)(ws + 86 * MB);
  unsigned short* Wori_bf = (unsigned short*)(ws + 88 * MB);
  unsigned short* WftT = (unsigned short*)(ws + 90 * MB);
  unsigned short* WfoT = (unsigned short*)(ws + 92 * MB);
  unsigned short* WfotT = (unsigned short*)(ws + 94 * MB);
  float* bc1 = (float*)(ws + 96 * MB);
  float* bc2 = bc1 + 1024;
  float* bc3 = bc2 + 1024;
  float* rt = bc3 + 1024;
  float* rf = rt + RowsT;
  float* uu = rf + RowsT;
  float* vv = uu + RowsT;

  const dim3 blk(256);

  // 1) quantize activations: origin->O_bf, target->T_bf
  conv_z<<<dim3(RowsT * Hn / 2048, 1, 2), blk, 0, stream>>>(origin, target, O_bf, T_bf);
  // 2) quantize W_tar, W_ori
  conv_z<<<dim3(Hn * Hn / 2048, 1, 2), blk, 0, stream>>>(W_tar, W_ori, Wtar_bf, Wori_bf);
  // 3) transpose W_ft, W_fo, W_fot -> [N][K] bf16
  transpose_w3<<<dim3(32, 32, 3), blk, 0, stream>>>(W_ft, W_fo, W_fot,
                                                    WftT, WfoT, WfotT, Hn, Hn);
  // 4) combined biases
  bias_combine<<<dim3(4, 3), blk, 0, stream>>>(b_tar, W_ft, b_ft, b_ori, W_fo, b_fo,
                                               b_ori, W_fot, b_fot, bc1, bc2, bc3);
  // 5) combined weights: Wc1^T=(W_tar@W_ft)^T, Wc2^T=(W_ori@W_fo)^T, Wc3^T=(W_ori@W_fot)^T
  mfma_gemm_w3<<<dim3(8, 8, 3), blk, 0, stream>>>(WftT, WfoT, WfotT,
                                                  Wtar_bf, Wori_bf, Wori_bf,
                                                  Wc1T, Wc2T, Wc3T, Hn, Hn);
  // 6) the three big GEMMs, one dispatch, XCD-swizzled
  mfma_gemm_big<<<dim3(1536), blk, 0, stream>>>(T_bf, O_bf, Wc1T, Wc2T, Wc3T,
                                                bc1, bc2, bc3, tar_bf, fc_bf, tpT);
  // 7) cosine norms
  rownorm_z<<<dim3(RowsT, 2), blk, 0, stream>>>(tar_bf, fc_bf, rt, rf, 1e-8f);
  // 8) Q = exp(cos/0.05)  (into dead O region)
  mfma_cos_exp<<<dim3(256), blk, 0, stream>>>(tar_bf, fc_bf, rt, rf, Qw);
  // 9) Sinkhorn via wide per-step kernels: u = 1/(Qv); v = 1/(Q^T u)
  u_step<true><<<dim3(RowsT / 4), blk, 0, stream>>>(Qw, vv, uu);
  v_step<<<dim3(Ln / 64, Bn), blk, 0, stream>>>(Qw, uu, vv);
  for (int it = 1; it < 5; ++it) {
    u_step<false><<<dim3(RowsT / 4), blk, 0, stream>>>(Qw, vv, uu);
    v_step<<<dim3(Ln / 64, Bn), blk, 0, stream>>>(Qw, uu, vv);
  }
  // 10) plan = l2norm_row(Q.v) -> bf16 (u cancels; over dead T region)
  plan_prep<<<dim3(RowsT), blk, 0, stream>>>(Qw, vv, plan_bf);
  // 11) out = plan @ tp + tar
  mfma_out<<<dim3(512), blk, 0, stream>>>(plan_bf, tpT, tar_bf, out);
  // 12) LayerNorm in-place
  ln_kernel<<<dim3(RowsT), blk, 0, stream>>>(out, ln_g, ln_b);
}